// Round 29
// baseline (171.946 us; speedup 1.0000x reference)
//
#include <hip/hip_runtime.h>
#include <math.h>

#define BB 4
#define HH 8
#define TT 4096
#define DD 64
#define NCC 64
#define WSZW 128
#define TPK 160          // widened bf16 top-k; f64 rescore picks exact top-128
#define MEMN 1
#define KVW (MEMN + WSZW)   // 129
constexpr float EPSF = 1e-5f;
constexpr float SCALE = 0.125f;  // 64^-0.5

typedef __attribute__((ext_vector_type(8))) short bf16x8;
typedef __attribute__((ext_vector_type(4))) float f32x4;

// HW packed f32->bf16 (RNE), 1 instruction vs ~7 for the manual bit-twiddle
static __device__ __forceinline__ unsigned int pk2(float a, float b) {
    unsigned int r;
    asm("v_cvt_pk_bf16_f32 %0, %1, %2" : "=v"(r) : "v"(a), "v"(b));
    return r;
}
static __device__ __forceinline__ bf16x8 pack8(float4 a, float4 b) {
    union { unsigned int u[4]; bf16x8 v; } r;
    r.u[0] = pk2(a.x, a.y); r.u[1] = pk2(a.z, a.w);
    r.u[2] = pk2(b.x, b.y); r.u[3] = pk2(b.z, b.w);
    return r.v;
}
static __device__ __forceinline__ unsigned mono16(unsigned u) {
    return (u ^ ((u & 0x8000u) ? 0xFFFFu : 0x8000u)) & 0xFFFFu;
}
static __device__ __forceinline__ unsigned long long mono64(double d) {
    unsigned long long b = (unsigned long long)__double_as_longlong(d);
    return b ^ (((long long)b < 0) ? ~0ULL : 0x8000000000000000ULL);
}
static __device__ __forceinline__ float bf2f(unsigned short u) {
    return __uint_as_float(((unsigned)u) << 16);
}

// ---------------- Kernel A: dists via split-bf16 MFMA -> bf16 dists ------------
__global__ __launch_bounds__(256, 4) void dists_kernel(
    const float* __restrict__ q, const float* __restrict__ k,
    const float* __restrict__ means,
    unsigned short* __restrict__ distsQ, unsigned short* __restrict__ distsK,
    float* __restrict__ aux_part, double* __restrict__ invn,
    int* __restrict__ counts)
{
    __shared__ __align__(16) unsigned short mhS[64 * 64];   // [c][d] swizzled chunks
    __shared__ __align__(16) unsigned short mlS[64 * 64];
    __shared__ __align__(16) unsigned short xhS[64 * 64];   // [tok][d]
    __shared__ __align__(16) unsigned short xlS[64 * 64];
    __shared__ float mqS[64];      // per-cluster ||m||^2
    __shared__ float ssnS[64];     // per-token ||xn||^2
    __shared__ float wMaxS[64 * 5];
    __shared__ int   wIdxS[64 * 5];

    const int chunks = (2 * TT) / 64;          // 128
    int bid0 = blockIdx.x;                     // 4096
    int bid = (bid0 & 7) * 512 + (bid0 >> 3);  // XCD-contiguous (4096 % 8 == 0)
    int bh = bid / chunks;
    int chunk = bid % chunks;
    int h = bh % HH;
    bool isQ = chunk < (TT / 64);
    int tbase = (isQ ? chunk : chunk - 64) * 64;
    const float* src = (isQ ? q : k) + ((size_t)bh * TT + tbase) * DD;
    unsigned short* dst = isQ ? distsQ : distsK;
    double* invdst = invn + (isQ ? 0 : (size_t)BB * HH * TT) + (size_t)bh * TT + tbase;

    int tid = threadIdx.x;

    // zero counts (replaces host memset): 4096 blocks x 32 ints = 131072
    if (tid < 32) counts[(size_t)bid0 * 32 + tid] = 0;

    int row = tid >> 2, part = tid & 3;        // row = cluster idx AND token idx

    // ---- stage means hi/lo (swizzled) + ||m||^2 ----
    {
        const float* mp = means + ((size_t)h * NCC + row) * DD + part * 16;
        float f[16];
        float msq = 0.f;
        #pragma unroll
        for (int i = 0; i < 4; ++i) {
            float4 va = *(const float4*)(mp + i * 4);
            f[i*4] = va.x; f[i*4+1] = va.y; f[i*4+2] = va.z; f[i*4+3] = va.w;
            msq += va.x*va.x + va.y*va.y + va.z*va.z + va.w*va.w;
        }
        msq += __shfl_xor(msq, 1);
        msq += __shfl_xor(msq, 2);
        if (part == 0) mqS[row] = msq;
        #pragma unroll
        for (int cc = 0; cc < 2; ++cc) {
            unsigned hw[4], lw[4];
            #pragma unroll
            for (int j2 = 0; j2 < 4; ++j2) {
                float a = f[cc*8 + j2*2], b = f[cc*8 + j2*2 + 1];
                unsigned p = pk2(a, b);
                float ha = __uint_as_float(p << 16);
                float hb = __uint_as_float(p & 0xFFFF0000u);
                hw[j2] = p; lw[j2] = pk2(a - ha, b - hb);
            }
            int ch = part * 2 + cc;
            int phys = ch ^ (row & 7);
            *reinterpret_cast<uint4*>(&mhS[row * 64 + phys * 8]) = (uint4){hw[0],hw[1],hw[2],hw[3]};
            *reinterpret_cast<uint4*>(&mlS[row * 64 + phys * 8]) = (uint4){lw[0],lw[1],lw[2],lw[3]};
        }
    }
    // ---- stage xn hi/lo (swizzled); f64 norm -> invn + ssn ----
    {
        const float* xp = src + (size_t)row * DD + part * 16;
        float f[16];
        double ssd = 0.0;
        #pragma unroll
        for (int i = 0; i < 4; ++i) {
            float4 va = *(const float4*)(xp + i * 4);
            f[i*4] = va.x; f[i*4+1] = va.y; f[i*4+2] = va.z; f[i*4+3] = va.w;
            ssd += (double)va.x*va.x + (double)va.y*va.y
                 + (double)va.z*va.z + (double)va.w*va.w;
        }
        ssd += __shfl_xor(ssd, 1);
        ssd += __shfl_xor(ssd, 2);
        double invd = 1.0 / fmax(sqrt(ssd), 1e-12);
        if (part == 0) {
            invdst[row] = invd;
            ssnS[row] = (float)(ssd * invd * invd);
        }
        float inv = (float)invd;
        #pragma unroll
        for (int i = 0; i < 16; ++i) f[i] *= inv;
        #pragma unroll
        for (int cc = 0; cc < 2; ++cc) {
            unsigned hw[4], lw[4];
            #pragma unroll
            for (int j2 = 0; j2 < 4; ++j2) {
                float a = f[cc*8 + j2*2], b = f[cc*8 + j2*2 + 1];
                unsigned p = pk2(a, b);
                float ha = __uint_as_float(p << 16);
                float hb = __uint_as_float(p & 0xFFFF0000u);
                hw[j2] = p; lw[j2] = pk2(a - ha, b - hb);
            }
            int ch = part * 2 + cc;
            int phys = ch ^ (row & 7);
            *reinterpret_cast<uint4*>(&xhS[row * 64 + phys * 8]) = (uint4){hw[0],hw[1],hw[2],hw[3]};
            *reinterpret_cast<uint4*>(&xlS[row * 64 + phys * 8]) = (uint4){lw[0],lw[1],lw[2],lw[3]};
        }
    }
    __syncthreads();

    int l = tid & 63, w = tid >> 6;
    int lr = l & 15, lg = l >> 4;

    // ---- A frags: cluster tile w (reused across all 4 token tiles) ----
    bf16x8 mhF[2], mlF[2];
    #pragma unroll
    for (int ks = 0; ks < 2; ++ks) {
        int r2 = w * 16 + lr;
        int phys = (ks * 4 + lg) ^ (r2 & 7);
        mhF[ks] = *reinterpret_cast<const bf16x8*>(&mhS[r2 * 64 + phys * 8]);
        mlF[ks] = *reinterpret_cast<const bf16x8*>(&mlS[r2 * 64 + phys * 8]);
    }

    // ---- GEMM: D[c = w*16+lg*4+r][tok = tt*16+lr], 6 mfma per token tile ----
    f32x4 accT[4];
    size_t rowb = (size_t)(bh * NCC) * TT;
    #pragma unroll
    for (int tt = 0; tt < 4; ++tt) {
        bf16x8 xhF[2], xlF[2];
        #pragma unroll
        for (int ks = 0; ks < 2; ++ks) {
            int r2 = tt * 16 + lr;
            int phys = (ks * 4 + lg) ^ (r2 & 7);
            xhF[ks] = *reinterpret_cast<const bf16x8*>(&xhS[r2 * 64 + phys * 8]);
            xlF[ks] = *reinterpret_cast<const bf16x8*>(&xlS[r2 * 64 + phys * 8]);
        }
        f32x4 a = (f32x4){0.f, 0.f, 0.f, 0.f};
        #pragma unroll
        for (int ks = 0; ks < 2; ++ks)
            a = __builtin_amdgcn_mfma_f32_16x16x32_bf16(mhF[ks], xhF[ks], a, 0, 0, 0);
        #pragma unroll
        for (int ks = 0; ks < 2; ++ks)
            a = __builtin_amdgcn_mfma_f32_16x16x32_bf16(mhF[ks], xlF[ks], a, 0, 0, 0);
        #pragma unroll
        for (int ks = 0; ks < 2; ++ks)
            a = __builtin_amdgcn_mfma_f32_16x16x32_bf16(mlF[ks], xhF[ks], a, 0, 0, 0);
        accT[tt] = a;
        #pragma unroll
        for (int r2 = 0; r2 < 4; ++r2) {
            int c = w * 16 + lg * 4 + r2;
            dst[rowb + (size_t)c * TT + tbase + tt * 16 + lr] =
                (unsigned short)(pk2(a[r2], a[r2]) & 0xFFFFu);
        }
    }

    // ---- argmax via shuffles (lane: token tt*16+lr, clusters w*16+lg*4+r) ----
    #pragma unroll
    for (int tt = 0; tt < 4; ++tt) {
        float bv = accT[tt][0]; int bc = w * 16 + lg * 4;
        #pragma unroll
        for (int r2 = 1; r2 < 4; ++r2)
            if (accT[tt][r2] > bv) { bv = accT[tt][r2]; bc = w * 16 + lg * 4 + r2; }
        #pragma unroll
        for (int off = 16; off <= 32; off <<= 1) {
            float ov = __shfl_xor(bv, off);
            int   oc = __shfl_xor(bc, off);
            if (ov > bv || (ov == bv && oc < bc)) { bv = ov; bc = oc; }
        }
        if (lg == 0) {
            wMaxS[(tt * 16 + lr) * 5 + w] = bv;
            wIdxS[(tt * 16 + lr) * 5 + w] = bc;
        }
    }
    __syncthreads();

    if (tid < 64) {
        float bv = -1e30f; int bc = 0;
        #pragma unroll
        for (int w2 = 0; w2 < 4; ++w2) {   // ascending cluster ranges
            float ov = wMaxS[tid * 5 + w2];
            int   oc = wIdxS[tid * 5 + w2];
            if (ov > bv || (ov == bv && oc < bc)) { bv = ov; bc = oc; }
        }
        float auxv = ssnS[tid] + mqS[bc] - 2.f * bv;
        #pragma unroll
        for (int off = 32; off; off >>= 1) auxv += __shfl_xor(auxv, off);
        if (tid == 0) aux_part[bid] = auxv;
    }
}

// ---------------- Kernel B: fused topk + f64 rescore, 640 threads -------------
// topk phase: threads 0..511 (threads 512+ carry zero counts through the
// 10-wave suffix scan -- algebraically inert). rescore phase: single pass,
// all 640 threads, 4 lanes/candidate (g = t>>2 in [0,160)).
__global__ __launch_bounds__(640) void topk_rescore_kernel(
    const unsigned short* __restrict__ dists,
    const float* __restrict__ q, const float* __restrict__ k,
    const float* __restrict__ means, const double* __restrict__ invn,
    int* __restrict__ idxQ, int* __restrict__ idxK,
    int* __restrict__ counts)
{
    int bid = blockIdx.x;
    int rid = (bid & 7) * 512 + (bid >> 3);   // 4096 % 8 == 0 -> bijective
    int side = rid >> 11;            // 0=Q, 1=K
    int row = rid & 2047;            // bh*NC + c
    int c = row & (NCC - 1);
    int bh = row >> 6;
    int h = bh % HH;

    const unsigned short* dv = dists + ((size_t)side * 2048 + row) * TT;
    int* outIdx = (side ? idxK : idxQ) + (size_t)row * WSZW;
    const float* xbase = (side ? k : q) + (size_t)bh * TT * DD;
    const double* invp = invn + (side ? (size_t)BB * HH * TT : 0) + (size_t)bh * TT;

    __shared__ int hist[4096];
    __shared__ int wtot[10];
    __shared__ int binSel, tgtS;
    __shared__ int nGtS, posS, eqPos;
    __shared__ int candL[TPK];
    __shared__ double   mD[DD];
    __shared__ unsigned hiS[TPK];
    __shared__ unsigned loS[TPK];
    __shared__ int      kiS[TPK];

    int t = threadIdx.x;
    int lane = t & 63, w = t >> 6;            // 10 waves

    // stage means f64 early (covered by topk barriers before first use)
    if (t < DD) mD[t] = (double)means[((size_t)h * NCC + c) * DD + t];

    unsigned u[8];
    bool act = t < 512;
    if (act) {
        uint4 a = *(const uint4*)(dv + t * 8);
        unsigned ws[4] = {a.x, a.y, a.z, a.w};
        #pragma unroll
        for (int i = 0; i < 4; ++i) {
            u[i*2]   = mono16(ws[i] & 0xFFFFu);
            u[i*2+1] = mono16(ws[i] >> 16);
        }
    } else {
        #pragma unroll
        for (int i = 0; i < 8; ++i) u[i] = 0;
    }

    int target = TPK;

    // ---- pass 1: top 12 bits over 4096 bins ----
    {
        if (act) {
            int4* hz = (int4*)&hist[t * 8];
            hz[0] = (int4){0,0,0,0}; hz[1] = (int4){0,0,0,0};
        }
        __syncthreads();
        if (act) {
            #pragma unroll
            for (int j = 0; j < 8; ++j) atomicAdd(&hist[u[j] >> 4], 1);
        }
        __syncthreads();
        int cnt[8], ls[8];
        if (act) {
            const int4* hp = (const int4*)&hist[t * 8];
            int4 c0 = hp[0], c1 = hp[1];
            cnt[0]=c0.x; cnt[1]=c0.y; cnt[2]=c0.z; cnt[3]=c0.w;
            cnt[4]=c1.x; cnt[5]=c1.y; cnt[6]=c1.z; cnt[7]=c1.w;
        } else {
            #pragma unroll
            for (int i = 0; i < 8; ++i) cnt[i] = 0;
        }
        int run = 0;
        #pragma unroll
        for (int i = 7; i >= 0; --i) { run += cnt[i]; ls[i] = run; }
        int S = run;
        #pragma unroll
        for (int off = 1; off < 64; off <<= 1) {
            int o = __shfl_down(S, off);
            if (lane + off < 64) S += o;
        }
        if (lane == 0) wtot[w] = S;
        __syncthreads();
        int after = 0;
        for (int ww = w + 1; ww < 10; ++ww) after += wtot[ww];
        int St1 = S - run + after;
        if (act) {
            #pragma unroll
            for (int i = 0; i < 8; ++i) {
                int sfxb = ls[i] + St1;
                if (sfxb >= target && sfxb - cnt[i] < target) {
                    binSel = t * 8 + i; tgtS = target - (sfxb - cnt[i]);
                }
            }
        }
        __syncthreads();
    }
    unsigned prefix12 = (unsigned)binSel;
    target = tgtS;
    __syncthreads();

    // ---- pass 2: low 4 bits (16 bins, lanes 0-15 of wave 0) ----
    if (t < 16) hist[t] = 0;
    __syncthreads();
    if (act) {
        #pragma unroll
        for (int j = 0; j < 8; ++j)
            if ((u[j] >> 4) == prefix12) atomicAdd(&hist[u[j] & 0xF], 1);
    }
    __syncthreads();
    if (t < 16) {
        int cnt = hist[t];
        int S = cnt;
        #pragma unroll
        for (int off = 1; off < 16; off <<= 1) {
            int o = __shfl_down(S, off);
            if (t + off < 16) S += o;
        }
        if (S >= target && S - cnt < target) binSel = t;
    }
    __syncthreads();
    unsigned pivot = (prefix12 << 4) | (unsigned)binSel;

    // ---- epilogue: compact candidates into LDS ----
    if (t == 0) { nGtS = 0; posS = 0; eqPos = 0; }
    __syncthreads();
    int myg = 0;
    #pragma unroll
    for (int j = 0; j < 8; ++j) myg += (u[j] > pivot) ? 1 : 0;
    if (act && myg) atomicAdd(&nGtS, myg);
    __syncthreads();
    int n_gt = nGtS;
    int n_need = TPK - n_gt;
    if (act) {
        #pragma unroll
        for (int j = 0; j < 8; ++j) {
            if (u[j] > pivot) {
                int p = atomicAdd(&posS, 1);
                candL[p] = t * 8 + j;
            } else if (u[j] == pivot) {
                int p = atomicAdd(&eqPos, 1);
                if (p < n_need) candL[n_gt + p] = t * 8 + j;
            }
        }
    }
    __syncthreads();

    // ---- rescore: f64 dot, 4 lanes/candidate, single pass (all 640) ----
    int g = t >> 2;                  // candidate 0..159
    int qt = t & 3;                  // quarter-row 0..3
    int tok = candL[g];
    const float* xp = xbase + (size_t)tok * DD + qt * 16;
    double inv = invp[tok];          // 4 lanes same addr -> broadcast
    double d0 = 0.0, d1 = 0.0;
    #pragma unroll
    for (int i = 0; i < 2; ++i) {
        float4 va = *(const float4*)(xp + i * 4);
        int d = qt * 16 + i * 4;
        d0 += (double)va.x * mD[d]   + (double)va.y * mD[d+1]
            + (double)va.z * mD[d+2] + (double)va.w * mD[d+3];
    }
    #pragma unroll
    for (int i = 2; i < 4; ++i) {
        float4 va = *(const float4*)(xp + i * 4);
        int d = qt * 16 + i * 4;
        d1 += (double)va.x * mD[d]   + (double)va.y * mD[d+1]
            + (double)va.z * mD[d+2] + (double)va.w * mD[d+3];
    }
    double dot = d0 + d1;
    dot += __shfl_xor(dot, 1); dot += __shfl_xor(dot, 2);
    double vv = dot * inv;           // identical across the 4-lane group
    unsigned long long key = mono64(vv);
    unsigned myhi = (unsigned)(key >> 32), mylo = (unsigned)key;
    if (qt == 0) { hiS[g] = myhi; loS[g] = mylo; kiS[g] = tok; }
    __syncthreads();

    // phase 1: branchless rank on 32-bit prefixes (1 LDS b32 read per iter)
    int rk = 0, eq = 0;
    #pragma unroll 8
    for (int i = 0; i < TPK / 4; ++i) {
        unsigned hj = hiS[qt * (TPK / 4) + i];
        rk += (hj > myhi) ? 1 : 0;
        eq += (hj == myhi) ? 1 : 0;
    }
    rk += __shfl_xor(rk, 1); rk += __shfl_xor(rk, 2);
    eq += __shfl_xor(eq, 1); eq += __shfl_xor(eq, 2);

    // phase 2 (rare): exact 64-bit + token recount when hi-prefix ties exist
    if (eq > 1) {
        int rk2 = 0;
        for (int i = 0; i < TPK / 4; ++i) {
            int j = qt * (TPK / 4) + i;
            unsigned hj = hiS[j];
            if (hj > myhi) rk2++;
            else if (hj == myhi) {
                unsigned lj = loS[j];
                if (lj > mylo || (lj == mylo && kiS[j] < tok)) rk2++;
            }
        }
        rk2 += __shfl_xor(rk2, 1); rk2 += __shfl_xor(rk2, 2);
        rk = rk2;
    }

    if (qt == 0 && rk < WSZW) {
        outIdx[rk] = tok;
        if (side == 0) atomicAdd(&counts[bh * TT + tok], 1);
    }
}

// ---------------- Kernel C: fused attn (blocks 0..2047) + scanfill (2048..2079) -
__global__ __launch_bounds__(512, 8) void attn_scanfill_kernel(
    const float* __restrict__ q, const float* __restrict__ k, const float* __restrict__ v,
    const float* __restrict__ mem_key, const float* __restrict__ mem_value,
    const int* __restrict__ idxQ, const int* __restrict__ idxK,
    unsigned short* __restrict__ so,
    const int* __restrict__ counts, int* __restrict__ offs, int* __restrict__ csr,
    const float* __restrict__ auxp, float* __restrict__ out)
{
    __shared__ __align__(16) unsigned char smemRaw[38144];
    int bid = blockIdx.x;

    if (bid >= 2048) {
        // ================= scanfill path (512 threads, 8 waves) =================
        int bh = bid - 2048;
        int t = threadIdx.x;
        int lane = t & 63, w = t >> 6;
        int* offsL = (int*)smemRaw;                   // 16384 B
        int* curL  = (int*)(smemRaw + 16384);         // 16384 B
        int* wsum  = (int*)(smemRaw + 32768);         // 32 B
        float* auxW = (float*)(smemRaw + 32800);      // 32 B

        // aux fold (loads only on bh==0; uniform barriers)
        float s = 0.f;
        if (bh == 0)
            for (int i = t; i < 4096; i += 512) s += auxp[i];
        #pragma unroll
        for (int off = 32; off; off >>= 1) s += __shfl_xor(s, off);
        if (lane == 0) auxW[w] = s;
        __syncthreads();
        if (bh == 0 && t == 0) {
            float a = 0.f;
            #pragma unroll
            for (int i = 0; i < 8; ++i) a += auxW[i];
            out[(size_t)BB * HH * TT * DD] =
                a * (1.0f / (float)(BB * HH * 2 * TT * DD));
        }

        // exclusive scan over counts[bh] via shfl
        const int* cb = counts + (size_t)bh * TT;
        int* ob = offs + (size_t)bh * TT;
        int loc[8]; int sum = 0;
        #pragma unroll
        for (int i = 0; i < 8; ++i) { loc[i] = sum; sum += cb[t * 8 + i]; }
        int incl = sum;
        #pragma unroll
        for (int off = 1; off < 64; off <<= 1) {
            int o = __shfl_up(incl, off);
            if (lane >= off) incl += o;
        }
        if (lane == 63) wsum[w] = incl;
        __syncthreads();
        if (t < 8) {
            int v2 = wsum[t];
            int inc2 = v2;
            #pragma unroll
            for (int off = 1; off < 8; off <<= 1) {
                int o = __shfl_up(inc2, off);
                if (t >= off) inc2 += o;
            }
            wsum[t] = inc2 - v2;                 // exclusive
        }
        __syncthreads();
        int ex = wsum[w] + incl - sum;
        #pragma unroll
        for (int i = 0; i < 8; ++i) {
            int o = ex + loc[i];
            ob[t * 8 + i] = o;
            offsL[t * 8 + i] = o;
            curL[t * 8 + i] = 0;
        }
        __syncthreads();

        // CSR fill (LDS atomics)
        const int* iq = idxQ + ((size_t)bh << 13);
        int* cs = csr + ((size_t)bh << 13);
        for (int i = t; i < 8192; i += 512) {
            int tok = iq[i];
            int p = offsL[tok] + atomicAdd(&curL[tok], 1);
            cs[p] = i;
        }
        return;
    }

    // ================= attn path ================================================
    unsigned short* KsS = (unsigned short*)smemRaw;            // 130*64 = 16640 B
    unsigned short* VtS = (unsigned short*)(smemRaw + 16640);  // 64*168*2 = 21504 B

    // XCD-bijective swizzle (2048 % 8 == 0): 256 consecutive blks per XCD
    int blk = (bid & 7) * 256 + (bid >> 3);
    int c = blk % NCC;
    int bh = blk / NCC;
    int h = bh % HH;

    int tid = threadIdx.x;
    int w = tid >> 6, l = tid & 63;
    int lr = l & 15, lg = l >> 4;

    const float* memK = mem_key   + ((size_t)h * NCC + c) * (MEMN * DD);
    const float* memV = mem_value + ((size_t)h * NCC + c) * (MEMN * DD);

    // ---- entry: resolve staging rows + issue ALL token-index gathers ----
    int stRow[3], stCh[3];
    const float *vsrcR[3], *ksrcR[3];
    #pragma unroll
    for (int s = 0; s < 3; ++s) {
        int idx = tid + s * 512;
        stRow[s] = idx >> 3; stCh[s] = idx & 7;
        vsrcR[s] = nullptr; ksrcR[s] = nullptr;
        if (idx < 1280 && stRow[s] < KVW) {
            if (stRow[s] == 0) { vsrcR[s] = memV; ksrcR[s] = memK; }
            else {
                int tk = idxK[(size_t)blk * WSZW + stRow[s] - 1];
                vsrcR[s] = v + ((size_t)bh * TT + tk) * DD;
                ksrcR[s] = k + ((size_t)bh * TT + tk) * DD;
            }
        }
    }

    // ---- Q frags (independent chase, overlaps everything) ----
    bf16x8 qf[2];
    {
        int tq = idxQ[(size_t)blk * WSZW + w * 16 + lr];
        const float* qp = q + ((size_t)bh * TT + tq) * DD;
        #pragma unroll
        for (int ks = 0; ks < 2; ++ks) {
            float4 a = *(const float4*)(qp + ks * 32 + lg * 8);
            float4 b = *(const float4*)(qp + ks * 32 + lg * 8 + 4);
            qf[ks] = pack8(a, b);
        }
    }

    // ---- V gather window (batched) ----
    uint4 vw[3];
    #pragma unroll
    for (int s = 0; s < 3; ++s) {
        vw[s] = (uint4){0,0,0,0};
        if (vsrcR[s]) {
            float4 a = *(const float4*)(vsrcR[s] + stCh[s] * 8);
            float4 b = *(const float4*)(vsrcR[s] + stCh[s] * 8 + 4);
            vw[s].x = pk2(a.x, a.y); vw[s].y = pk2(a.z, a.w);
            vw[s].z = pk2(b.x, b.y); vw[s].w = pk2(b.z, b.w);
        }
    }
    // ---- K gather window (batched) ----
    uint4 kw[3];
    #pragma unroll
    for (int s = 0; s < 3; ++s) {
        kw[s] = (uint4){0,0,0,0};
        if (ksrcR[s]) {
            float4 a = *(const float4*)(ksrcR[s] + stCh[s] * 8);
            float4 b = *(const float4*)(ksrcR[s] + stCh[s] * 8 + 4);
            kw[s].x = pk2(a.x, a.y); kw[s].y = pk2(a.z, a.w);
            kw[s].z = pk2(b.x, b.y); kw[s].w = pk2(b.z, b.w);
        }
    }

    // ---- P1: V -> row-major swizzled (valid rows only) ----
    #pragma unroll
    for (int s = 0; s < 3; ++s)
        if (vsrcR[s])
            *reinterpret_cast<uint4*>(
                &KsS[stRow[s] * 64 + ((stCh[s] ^ (stRow[s] & 7)) * 8)]) = vw[s];
    __syncthreads();

    // ---- P2: Vt column segments -> regs (clamped rows; broadcast-class) ----
    unsigned short vreg[3][8];
    #pragma unroll
    for (int s = 0; s < 3; ++s) {
        int idx = tid + s * 512;
        if (idx < 1280) {
            int d = idx & 63, rowblk = idx >> 6;
            #pragma unroll
            for (int i = 0; i < 8; ++i) {
                int row = rowblk * 8 + i;
                int pr = (row < KVW) ? row : 128;
                vreg[s][i] = KsS[pr * 64 + (((d >> 3) ^ (pr & 7)) * 8) + (d & 7)];
            }
        }
    }
    __syncthreads();

    // ---- P3: write Vt (b128 rows) + K (valid rows only) ----
    #pragma unroll
    for (int s = 0; s < 3; ++s) {
        int idx = tid + s * 512;
        if (idx < 1280) {
            int d = idx & 63, rowblk = idx >> 6;
            uint4 ow;
            ow.x = (unsigned)vreg[s][0] | ((unsigned)vreg[s][1] << 16);
            ow.y = (unsigned)vreg[s][2] | ((unsigned)vreg[s][3] << 16);
            ow.z = (unsigned)vreg[s][4] | ((unsigned)vreg[s][5] << 16);
            ow.w = (unsigned)vreg[s][6] | ((unsigned)vreg[s][7] << 16);
            *reinterpret_cast<uint4*>(&VtS[d * 168 + rowblk * 8]) = ow;
        }
    }
    #pragma unroll
    for (int s = 0; s < 3; ++s)
        if (ksrcR[s])
            *reinterpret_cast<uint4*>(
                &KsS[stRow[s] * 64 + ((stCh[s] ^ (stRow[s] & 7)) * 8)]) = kw[s];
    __syncthreads();

    // ---- compute (swapped QK^T, P in regs, Vt b128 B-frags) ----
    f32x4 acc[4];
    #pragma unroll
    for (int dt = 0; dt < 4; ++dt) acc[dt] = (f32x4){0.f, 0.f, 0.f, 0.f};
    float s_sum = 0.f;

    int src0 = lr + ((lg & 1) * 2) * 16;
    int src1 = src0 + 16;
    bool hi = (lg >> 1) != 0;

    for (int kb = 0; kb < 5; ++kb) {
        bf16x8 kf[2][2];
        #pragma unroll
        for (int kvt = 0; kvt < 2; ++kvt)
            #pragma unroll
            for (int ks = 0; ks < 2; ++ks) {
                int row = kb * 32 + kvt * 16 + lr;
                int pr = (row < KVW) ? row : 128;
                int phys = (ks * 4 + lg) ^ (pr & 7);
                kf[kvt][ks] = *reinterpret_cast<const bf16x8*>(&KsS[pr * 64 + phys * 8]);
            }
        __builtin_amdgcn_s_setprio(1);
        unsigned pk[2][2];
        #pragma unroll
        for (int kvt = 0; kvt < 2; ++kvt) {
            f32x4 sf = __builtin_amdgcn_mfma_f32_16x16x32_bf16(
                kf[kvt][0], qf[0], (f32x4){0.f,0.f,0.f,0.f}, 0, 0, 0);
            sf = __builtin_amdgcn_mfma_f32_16x16x32_bf16(kf[kvt][1], qf[1], sf, 0, 0, 0);
            float e[4];
            #pragma unroll
            for (int r = 0; r < 4; ++r) {
                int kv = kb * 32 + kvt * 16 + lg * 4 + r;
                e[r] = (kv < KVW) ? __expf(sf[r] * SCALE) : 0.f;
                s_sum += e[r];
            }
            pk[kvt][0] = pk2(e[0], e[1]);
            pk[kvt][1] = pk2(e[2], e[3]);
        }
        unsigned a00 = __shfl(pk[0][0], src0), a01 = __shfl(pk[0][1], src0);
        unsigned a10 = __shfl(pk[1][0], src0), a11 = __shfl(pk[1][1], src0);
        unsigned b00 = __shfl(pk[0][0], src1), b01 = __shfl(pk[0][1], src1);
        unsigned b10 = __shfl(pk[1][0], src1), b11 = __shfl(pk[1][1], src1);
        union { unsigned u[4]; bf16x8 v; } pu;
        pu.u[0] = hi ? a10 : a00;
        pu.u[1] = hi ? a11 : a01;
        pu.u[2] = hi ? b10 : b00;
        pu.u[3] = hi ? b11 : b01;
        #pragma unroll
        for (int dt = 0; dt < 4; ++dt) {
            bf16x8 vf = *reinterpret_cast<const bf16x8*>(
                &VtS[(dt * 16 + lr) * 168 + kb * 32 + lg * 8]);
            acc[dt] = __builtin_amdgcn_mfma_f32_16x16x32_bf16(pu.v, vf, acc[dt], 0, 0, 0);
        }
        __builtin_amdgcn_s_setprio(0);
    }

    s_sum += __shfl_xor(s_sum, 16);
    s_sum += __shfl_xor(s_sum, 32);
    float sinv[4];
    #pragma unroll
    for (int r = 0; r < 4; ++r)
        sinv[r] = 1.f / __shfl(s_sum, lg * 4 + r);

    // ---- store O as bf16 ----
    #pragma unroll
    for (int r = 0; r < 4; ++r) {
        int row = w * 16 + lg * 4 + r;
        unsigned short* op = so + (((size_t)blk * WSZW + row) * DD);
        #pragma unroll
        for (int dt = 0; dt < 4; ++dt) {
            float ov = acc[dt][r] * sinv[r];
            op[dt * 16 + lr] = (unsigned short)(pk2(ov, ov) & 0xFFFFu);
        }
    }
}

// ---------------- Kernel H: gather-reduce (bf16 so), pair-batched + XCD swz ----
__global__ __launch_bounds__(256) void reduce_kernel(
    const unsigned short* __restrict__ so, const int* __restrict__ counts,
    const int* __restrict__ offs, const int* __restrict__ csr,
    float* __restrict__ out)
{
    int b0 = blockIdx.x;
    int b = (b0 & 7) * 4096 + (b0 >> 3);     // 32768 % 8 == 0 -> bijective
    int gt = b * 4 + (threadIdx.x >> 6);
    int lane = threadIdx.x & 63;
    int bh = gt >> 12;
    int n = counts[gt];
    int st = offs[gt];
    const int* cs = csr + ((size_t)bh << 13);
    const unsigned short* sob = so + (((size_t)bh << 13) * DD);
    float acc = 0.f;
    int j = 0;
    for (; j + 2 <= n; j += 2) {             // pair-batched: 2 idx, then 2 rows
        int s0 = cs[st + j], s1 = cs[st + j + 1];
        float v0 = bf2f(sob[(size_t)s0 * DD + lane]);
        float v1 = bf2f(sob[(size_t)s1 * DD + lane]);
        acc += v0 + v1;
    }
    if (j < n) acc += bf2f(sob[(size_t)cs[st + j] * DD + lane]);
    out[(size_t)gt * DD + lane] = acc / ((float)n + EPSF);
}

extern "C" void kernel_launch(void* const* d_in, const int* in_sizes, int n_in,
                              void* d_out, int out_size, void* d_ws, size_t ws_size,
                              hipStream_t stream) {
    const float* q        = (const float*)d_in[0];
    const float* k        = (const float*)d_in[1];
    const float* v        = (const float*)d_in[2];
    const float* means    = (const float*)d_in[3];
    const float* mem_key  = (const float*)d_in[4];
    const float* mem_val  = (const float*)d_in[5];
    float* out = (float*)d_out;

    const size_t nRows = (size_t)BB * HH * NCC;             // 2048
    const size_t nTok  = (size_t)BB * HH * TT;              // 131072
    const size_t nDist = (size_t)BB * HH * NCC * TT;        // 16777216
    unsigned short* distsQ = (unsigned short*)d_ws;         // bf16, 16.7M (distsK contiguous after)
    unsigned short* distsK = distsQ + nDist;
    unsigned short* so     = distsQ;                        // bf16, aliases dists (written after rescore)
    int*   idxQ   = (int*)(distsK + nDist);                 // 262144 i
    int*   idxK   = idxQ + nRows * WSZW;                    // 262144 i
    int*   counts = idxK + nRows * WSZW;                    // 131072 i (zeroed in dists_kernel)
    float* auxp   = (float*)(counts + nTok);                // 4096 f (per-block partials)
    int*   offs   = (int*)(auxp + 4096);                    // 131072 i
    int*   csr    = offs + nTok;                            // 262144 i
    uintptr_t ip  = (uintptr_t)(csr + nTok * 2);
    ip = (ip + 15) & ~(uintptr_t)15;
    double* invn  = (double*)ip;                            // 2*131072 d (Q then K)

    dists_kernel<<<dim3(BB * HH * (2 * TT / 64)), dim3(256), 0, stream>>>(
        q, k, means, distsQ, distsK, auxp, invn, counts);
    topk_rescore_kernel<<<dim3((unsigned)(2 * nRows)), dim3(640), 0, stream>>>(
        distsQ, q, k, means, invn, idxQ, idxK, counts);
    attn_scanfill_kernel<<<dim3((unsigned)(nRows + BB * HH)), dim3(512), 0, stream>>>(
        q, k, v, mem_key, mem_val, idxQ, idxK, so,
        counts, offs, csr, auxp, out);
    reduce_kernel<<<dim3((unsigned)(nTok / 4)), dim3(256), 0, stream>>>(
        so, counts, offs, csr, out);
}

// Round 30
// 158.943 us; speedup vs baseline: 1.0818x; 1.0818x over previous
//
#include <hip/hip_runtime.h>
#include <math.h>

#define BB 4
#define HH 8
#define TT 4096
#define DD 64
#define NCC 64
#define WSZW 128
#define TPK 160          // widened bf16 top-k; f64 rescore picks exact top-128
#define MEMN 1
#define KVW (MEMN + WSZW)   // 129
constexpr float EPSF = 1e-5f;
constexpr float SCALE = 0.125f;  // 64^-0.5

typedef __attribute__((ext_vector_type(8))) short bf16x8;
typedef __attribute__((ext_vector_type(4))) float f32x4;

// HW packed f32->bf16 (RNE), 1 instruction vs ~7 for the manual bit-twiddle
static __device__ __forceinline__ unsigned int pk2(float a, float b) {
    unsigned int r;
    asm("v_cvt_pk_bf16_f32 %0, %1, %2" : "=v"(r) : "v"(a), "v"(b));
    return r;
}
static __device__ __forceinline__ bf16x8 pack8(float4 a, float4 b) {
    union { unsigned int u[4]; bf16x8 v; } r;
    r.u[0] = pk2(a.x, a.y); r.u[1] = pk2(a.z, a.w);
    r.u[2] = pk2(b.x, b.y); r.u[3] = pk2(b.z, b.w);
    return r.v;
}
static __device__ __forceinline__ unsigned mono16(unsigned u) {
    return (u ^ ((u & 0x8000u) ? 0xFFFFu : 0x8000u)) & 0xFFFFu;
}
static __device__ __forceinline__ unsigned long long mono64(double d) {
    unsigned long long b = (unsigned long long)__double_as_longlong(d);
    return b ^ (((long long)b < 0) ? ~0ULL : 0x8000000000000000ULL);
}
static __device__ __forceinline__ float bf2f(unsigned short u) {
    return __uint_as_float(((unsigned)u) << 16);
}

// ---------------- Kernel A: dists via split-bf16 MFMA -> bf16 dists ------------
__global__ __launch_bounds__(256, 4) void dists_kernel(
    const float* __restrict__ q, const float* __restrict__ k,
    const float* __restrict__ means,
    unsigned short* __restrict__ distsQ, unsigned short* __restrict__ distsK,
    float* __restrict__ aux_part, double* __restrict__ invn,
    int* __restrict__ counts)
{
    __shared__ __align__(16) unsigned short mhS[64 * 64];   // [c][d] swizzled chunks
    __shared__ __align__(16) unsigned short mlS[64 * 64];
    __shared__ __align__(16) unsigned short xhS[64 * 64];   // [tok][d]
    __shared__ __align__(16) unsigned short xlS[64 * 64];
    __shared__ float mqS[64];      // per-cluster ||m||^2
    __shared__ float ssnS[64];     // per-token ||xn||^2
    __shared__ float wMaxS[64 * 5];
    __shared__ int   wIdxS[64 * 5];

    const int chunks = (2 * TT) / 64;          // 128
    int bid0 = blockIdx.x;                     // 4096
    int bid = (bid0 & 7) * 512 + (bid0 >> 3);  // XCD-contiguous (4096 % 8 == 0)
    int bh = bid / chunks;
    int chunk = bid % chunks;
    int h = bh % HH;
    bool isQ = chunk < (TT / 64);
    int tbase = (isQ ? chunk : chunk - 64) * 64;
    const float* src = (isQ ? q : k) + ((size_t)bh * TT + tbase) * DD;
    unsigned short* dst = isQ ? distsQ : distsK;
    double* invdst = invn + (isQ ? 0 : (size_t)BB * HH * TT) + (size_t)bh * TT + tbase;

    int tid = threadIdx.x;

    // zero counts (replaces host memset): 4096 blocks x 32 ints = 131072
    if (tid < 32) counts[(size_t)bid0 * 32 + tid] = 0;

    int row = tid >> 2, part = tid & 3;        // row = cluster idx AND token idx

    // ---- stage means hi/lo (swizzled) + ||m||^2 ----
    {
        const float* mp = means + ((size_t)h * NCC + row) * DD + part * 16;
        float f[16];
        float msq = 0.f;
        #pragma unroll
        for (int i = 0; i < 4; ++i) {
            float4 va = *(const float4*)(mp + i * 4);
            f[i*4] = va.x; f[i*4+1] = va.y; f[i*4+2] = va.z; f[i*4+3] = va.w;
            msq += va.x*va.x + va.y*va.y + va.z*va.z + va.w*va.w;
        }
        msq += __shfl_xor(msq, 1);
        msq += __shfl_xor(msq, 2);
        if (part == 0) mqS[row] = msq;
        #pragma unroll
        for (int cc = 0; cc < 2; ++cc) {
            unsigned hw[4], lw[4];
            #pragma unroll
            for (int j2 = 0; j2 < 4; ++j2) {
                float a = f[cc*8 + j2*2], b = f[cc*8 + j2*2 + 1];
                unsigned p = pk2(a, b);
                float ha = __uint_as_float(p << 16);
                float hb = __uint_as_float(p & 0xFFFF0000u);
                hw[j2] = p; lw[j2] = pk2(a - ha, b - hb);
            }
            int ch = part * 2 + cc;
            int phys = ch ^ (row & 7);
            *reinterpret_cast<uint4*>(&mhS[row * 64 + phys * 8]) = (uint4){hw[0],hw[1],hw[2],hw[3]};
            *reinterpret_cast<uint4*>(&mlS[row * 64 + phys * 8]) = (uint4){lw[0],lw[1],lw[2],lw[3]};
        }
    }
    // ---- stage xn hi/lo (swizzled); f64 norm -> invn + ssn ----
    {
        const float* xp = src + (size_t)row * DD + part * 16;
        float f[16];
        double ssd = 0.0;
        #pragma unroll
        for (int i = 0; i < 4; ++i) {
            float4 va = *(const float4*)(xp + i * 4);
            f[i*4] = va.x; f[i*4+1] = va.y; f[i*4+2] = va.z; f[i*4+3] = va.w;
            ssd += (double)va.x*va.x + (double)va.y*va.y
                 + (double)va.z*va.z + (double)va.w*va.w;
        }
        ssd += __shfl_xor(ssd, 1);
        ssd += __shfl_xor(ssd, 2);
        double invd = 1.0 / fmax(sqrt(ssd), 1e-12);
        if (part == 0) {
            invdst[row] = invd;
            ssnS[row] = (float)(ssd * invd * invd);
        }
        float inv = (float)invd;
        #pragma unroll
        for (int i = 0; i < 16; ++i) f[i] *= inv;
        #pragma unroll
        for (int cc = 0; cc < 2; ++cc) {
            unsigned hw[4], lw[4];
            #pragma unroll
            for (int j2 = 0; j2 < 4; ++j2) {
                float a = f[cc*8 + j2*2], b = f[cc*8 + j2*2 + 1];
                unsigned p = pk2(a, b);
                float ha = __uint_as_float(p << 16);
                float hb = __uint_as_float(p & 0xFFFF0000u);
                hw[j2] = p; lw[j2] = pk2(a - ha, b - hb);
            }
            int ch = part * 2 + cc;
            int phys = ch ^ (row & 7);
            *reinterpret_cast<uint4*>(&xhS[row * 64 + phys * 8]) = (uint4){hw[0],hw[1],hw[2],hw[3]};
            *reinterpret_cast<uint4*>(&xlS[row * 64 + phys * 8]) = (uint4){lw[0],lw[1],lw[2],lw[3]};
        }
    }
    __syncthreads();

    int l = tid & 63, w = tid >> 6;
    int lr = l & 15, lg = l >> 4;

    // ---- A frags: cluster tile w (reused across all 4 token tiles) ----
    bf16x8 mhF[2], mlF[2];
    #pragma unroll
    for (int ks = 0; ks < 2; ++ks) {
        int r2 = w * 16 + lr;
        int phys = (ks * 4 + lg) ^ (r2 & 7);
        mhF[ks] = *reinterpret_cast<const bf16x8*>(&mhS[r2 * 64 + phys * 8]);
        mlF[ks] = *reinterpret_cast<const bf16x8*>(&mlS[r2 * 64 + phys * 8]);
    }

    // ---- GEMM: D[c = w*16+lg*4+r][tok = tt*16+lr], 6 mfma per token tile ----
    f32x4 accT[4];
    size_t rowb = (size_t)(bh * NCC) * TT;
    #pragma unroll
    for (int tt = 0; tt < 4; ++tt) {
        bf16x8 xhF[2], xlF[2];
        #pragma unroll
        for (int ks = 0; ks < 2; ++ks) {
            int r2 = tt * 16 + lr;
            int phys = (ks * 4 + lg) ^ (r2 & 7);
            xhF[ks] = *reinterpret_cast<const bf16x8*>(&xhS[r2 * 64 + phys * 8]);
            xlF[ks] = *reinterpret_cast<const bf16x8*>(&xlS[r2 * 64 + phys * 8]);
        }
        f32x4 a = (f32x4){0.f, 0.f, 0.f, 0.f};
        #pragma unroll
        for (int ks = 0; ks < 2; ++ks)
            a = __builtin_amdgcn_mfma_f32_16x16x32_bf16(mhF[ks], xhF[ks], a, 0, 0, 0);
        #pragma unroll
        for (int ks = 0; ks < 2; ++ks)
            a = __builtin_amdgcn_mfma_f32_16x16x32_bf16(mhF[ks], xlF[ks], a, 0, 0, 0);
        #pragma unroll
        for (int ks = 0; ks < 2; ++ks)
            a = __builtin_amdgcn_mfma_f32_16x16x32_bf16(mlF[ks], xhF[ks], a, 0, 0, 0);
        accT[tt] = a;
        #pragma unroll
        for (int r2 = 0; r2 < 4; ++r2) {
            int c = w * 16 + lg * 4 + r2;
            dst[rowb + (size_t)c * TT + tbase + tt * 16 + lr] =
                (unsigned short)(pk2(a[r2], a[r2]) & 0xFFFFu);
        }
    }

    // ---- argmax via shuffles (lane: token tt*16+lr, clusters w*16+lg*4+r) ----
    #pragma unroll
    for (int tt = 0; tt < 4; ++tt) {
        float bv = accT[tt][0]; int bc = w * 16 + lg * 4;
        #pragma unroll
        for (int r2 = 1; r2 < 4; ++r2)
            if (accT[tt][r2] > bv) { bv = accT[tt][r2]; bc = w * 16 + lg * 4 + r2; }
        #pragma unroll
        for (int off = 16; off <= 32; off <<= 1) {
            float ov = __shfl_xor(bv, off);
            int   oc = __shfl_xor(bc, off);
            if (ov > bv || (ov == bv && oc < bc)) { bv = ov; bc = oc; }
        }
        if (lg == 0) {
            wMaxS[(tt * 16 + lr) * 5 + w] = bv;
            wIdxS[(tt * 16 + lr) * 5 + w] = bc;
        }
    }
    __syncthreads();

    if (tid < 64) {
        float bv = -1e30f; int bc = 0;
        #pragma unroll
        for (int w2 = 0; w2 < 4; ++w2) {   // ascending cluster ranges
            float ov = wMaxS[tid * 5 + w2];
            int   oc = wIdxS[tid * 5 + w2];
            if (ov > bv || (ov == bv && oc < bc)) { bv = ov; bc = oc; }
        }
        float auxv = ssnS[tid] + mqS[bc] - 2.f * bv;
        #pragma unroll
        for (int off = 32; off; off >>= 1) auxv += __shfl_xor(auxv, off);
        if (tid == 0) aux_part[bid] = auxv;
    }
}

// ---------------- Kernel B: fused topk (LDS candidates) + f64 rescore ----------
// Per block = one (side,row): 2-pass 12/4 radix topk writes the 160-candidate
// set to LDS, then the exact f64 rescore runs in the same block (512 threads,
// 4 lanes/candidate in 2 passes of 128+32 groups; no barrier between the two
// passes' bodies, so their loads overlap). 512 thr = 8 waves -> 4 blocks/CU.
__global__ __launch_bounds__(512) void topk_rescore_kernel(
    const unsigned short* __restrict__ dists,
    const float* __restrict__ q, const float* __restrict__ k,
    const float* __restrict__ means, const double* __restrict__ invn,
    int* __restrict__ idxQ, int* __restrict__ idxK,
    int* __restrict__ counts)
{
    int bid = blockIdx.x;
    int rid = (bid & 7) * 512 + (bid >> 3);   // 4096 % 8 == 0 -> bijective
    int side = rid >> 11;            // 0=Q, 1=K
    int row = rid & 2047;            // bh*NC + c
    int c = row & (NCC - 1);
    int bh = row >> 6;
    int h = bh % HH;

    const unsigned short* dv = dists + ((size_t)side * 2048 + row) * TT;
    int* outIdx = (side ? idxK : idxQ) + (size_t)row * WSZW;
    const float* xbase = (side ? k : q) + (size_t)bh * TT * DD;
    const double* invp = invn + (side ? (size_t)BB * HH * TT : 0) + (size_t)bh * TT;

    __shared__ int hist[4096];
    __shared__ int wtot[8];
    __shared__ int binSel, tgtS;
    __shared__ int nGtS, posS, eqPos;
    __shared__ int candL[TPK];
    __shared__ double   mD[DD];
    __shared__ unsigned hiS[TPK];
    __shared__ unsigned loS[TPK];
    __shared__ int      kiS[TPK];

    int t = threadIdx.x;
    int lane = t & 63, w = t >> 6;            // 8 waves

    // stage means f64 early (covered by topk barriers before first use)
    if (t < DD) mD[t] = (double)means[((size_t)h * NCC + c) * DD + t];

    unsigned u[8];
    {
        uint4 a = *(const uint4*)(dv + t * 8);
        unsigned ws[4] = {a.x, a.y, a.z, a.w};
        #pragma unroll
        for (int i = 0; i < 4; ++i) {
            u[i*2]   = mono16(ws[i] & 0xFFFFu);
            u[i*2+1] = mono16(ws[i] >> 16);
        }
    }

    int target = TPK;

    // ---- pass 1: top 12 bits over 4096 bins ----
    {
        int4* hz = (int4*)&hist[t * 8];
        hz[0] = (int4){0,0,0,0}; hz[1] = (int4){0,0,0,0};
        __syncthreads();
        #pragma unroll
        for (int j = 0; j < 8; ++j) atomicAdd(&hist[u[j] >> 4], 1);
        __syncthreads();
        int cnt[8], ls[8];
        {
            const int4* hp = (const int4*)&hist[t * 8];
            int4 c0 = hp[0], c1 = hp[1];
            cnt[0]=c0.x; cnt[1]=c0.y; cnt[2]=c0.z; cnt[3]=c0.w;
            cnt[4]=c1.x; cnt[5]=c1.y; cnt[6]=c1.z; cnt[7]=c1.w;
        }
        int run = 0;
        #pragma unroll
        for (int i = 7; i >= 0; --i) { run += cnt[i]; ls[i] = run; }
        int S = run;
        #pragma unroll
        for (int off = 1; off < 64; off <<= 1) {
            int o = __shfl_down(S, off);
            if (lane + off < 64) S += o;
        }
        if (lane == 0) wtot[w] = S;
        __syncthreads();
        int after = 0;
        for (int ww = w + 1; ww < 8; ++ww) after += wtot[ww];
        int St1 = S - run + after;
        #pragma unroll
        for (int i = 0; i < 8; ++i) {
            int sfxb = ls[i] + St1;
            if (sfxb >= target && sfxb - cnt[i] < target) {
                binSel = t * 8 + i; tgtS = target - (sfxb - cnt[i]);
            }
        }
        __syncthreads();
    }
    unsigned prefix12 = (unsigned)binSel;
    target = tgtS;
    __syncthreads();

    // ---- pass 2: low 4 bits (16 bins, lanes 0-15 of wave 0) ----
    if (t < 16) hist[t] = 0;
    __syncthreads();
    #pragma unroll
    for (int j = 0; j < 8; ++j)
        if ((u[j] >> 4) == prefix12) atomicAdd(&hist[u[j] & 0xF], 1);
    __syncthreads();
    if (t < 16) {
        int cnt = hist[t];
        int S = cnt;
        #pragma unroll
        for (int off = 1; off < 16; off <<= 1) {
            int o = __shfl_down(S, off);
            if (t + off < 16) S += o;
        }
        if (S >= target && S - cnt < target) binSel = t;
    }
    __syncthreads();
    unsigned pivot = (prefix12 << 4) | (unsigned)binSel;

    // ---- epilogue: compact candidates into LDS ----
    if (t == 0) { nGtS = 0; posS = 0; eqPos = 0; }
    __syncthreads();
    int myg = 0;
    #pragma unroll
    for (int j = 0; j < 8; ++j) myg += (u[j] > pivot) ? 1 : 0;
    if (myg) atomicAdd(&nGtS, myg);
    __syncthreads();
    int n_gt = nGtS;
    int n_need = TPK - n_gt;
    #pragma unroll
    for (int j = 0; j < 8; ++j) {
        if (u[j] > pivot) {
            int p = atomicAdd(&posS, 1);
            candL[p] = t * 8 + j;
        } else if (u[j] == pivot) {
            int p = atomicAdd(&eqPos, 1);
            if (p < n_need) candL[n_gt + p] = t * 8 + j;
        }
    }
    __syncthreads();

    // ---- rescore: f64 dot, 4 lanes/candidate, 2 passes (128 + 32 groups) ----
    int qt = t & 3;
    #pragma unroll
    for (int base = 0; base < TPK; base += 128) {
        int g = base + (t >> 2);
        if (g < TPK) {
            int tok = candL[g];
            const float* xp = xbase + (size_t)tok * DD + qt * 16;
            double inv = invp[tok];
            double d0 = 0.0, d1 = 0.0;
            #pragma unroll
            for (int i = 0; i < 2; ++i) {
                float4 va = *(const float4*)(xp + i * 4);
                int d = qt * 16 + i * 4;
                d0 += (double)va.x * mD[d]   + (double)va.y * mD[d+1]
                    + (double)va.z * mD[d+2] + (double)va.w * mD[d+3];
            }
            #pragma unroll
            for (int i = 2; i < 4; ++i) {
                float4 va = *(const float4*)(xp + i * 4);
                int d = qt * 16 + i * 4;
                d1 += (double)va.x * mD[d]   + (double)va.y * mD[d+1]
                    + (double)va.z * mD[d+2] + (double)va.w * mD[d+3];
            }
            double dot = d0 + d1;
            dot += __shfl_xor(dot, 1); dot += __shfl_xor(dot, 2);
            double vv = dot * inv;
            unsigned long long key = mono64(vv);
            if (qt == 0) {
                hiS[g] = (unsigned)(key >> 32);
                loS[g] = (unsigned)key;
                kiS[g] = tok;
            }
        }
    }
    __syncthreads();

    // ---- rank (branchless u32 prefixes; rare exact fallback) ----
    #pragma unroll
    for (int base = 0; base < TPK; base += 128) {
        int g = base + (t >> 2);
        if (g < TPK) {
            unsigned myhi = hiS[g], mylo = loS[g];
            int tok = kiS[g];
            int rk = 0, eq = 0;
            #pragma unroll 8
            for (int i = 0; i < TPK / 4; ++i) {
                unsigned hj = hiS[qt * (TPK / 4) + i];
                rk += (hj > myhi) ? 1 : 0;
                eq += (hj == myhi) ? 1 : 0;
            }
            rk += __shfl_xor(rk, 1); rk += __shfl_xor(rk, 2);
            eq += __shfl_xor(eq, 1); eq += __shfl_xor(eq, 2);
            if (eq > 1) {
                int rk2 = 0;
                for (int i = 0; i < TPK / 4; ++i) {
                    int j = qt * (TPK / 4) + i;
                    unsigned hj = hiS[j];
                    if (hj > myhi) rk2++;
                    else if (hj == myhi) {
                        unsigned lj = loS[j];
                        if (lj > mylo || (lj == mylo && kiS[j] < tok)) rk2++;
                    }
                }
                rk2 += __shfl_xor(rk2, 1); rk2 += __shfl_xor(rk2, 2);
                rk = rk2;
            }
            if (qt == 0 && rk < WSZW) {
                outIdx[rk] = tok;
                if (side == 0) atomicAdd(&counts[bh * TT + tok], 1);
            }
        }
    }
}

// ---------------- Kernel C: fused attn (blocks 0..2047) + scanfill (2048..2079) -
__global__ __launch_bounds__(512, 8) void attn_scanfill_kernel(
    const float* __restrict__ q, const float* __restrict__ k, const float* __restrict__ v,
    const float* __restrict__ mem_key, const float* __restrict__ mem_value,
    const int* __restrict__ idxQ, const int* __restrict__ idxK,
    unsigned short* __restrict__ so,
    const int* __restrict__ counts, int* __restrict__ offs, int* __restrict__ csr,
    const float* __restrict__ auxp, float* __restrict__ out)
{
    __shared__ __align__(16) unsigned char smemRaw[38144];
    int bid = blockIdx.x;

    if (bid >= 2048) {
        // ================= scanfill path (512 threads, 8 waves) =================
        int bh = bid - 2048;
        int t = threadIdx.x;
        int lane = t & 63, w = t >> 6;
        int* offsL = (int*)smemRaw;                   // 16384 B
        int* curL  = (int*)(smemRaw + 16384);         // 16384 B
        int* wsum  = (int*)(smemRaw + 32768);         // 32 B
        float* auxW = (float*)(smemRaw + 32800);      // 32 B

        // aux fold (loads only on bh==0; uniform barriers)
        float s = 0.f;
        if (bh == 0)
            for (int i = t; i < 4096; i += 512) s += auxp[i];
        #pragma unroll
        for (int off = 32; off; off >>= 1) s += __shfl_xor(s, off);
        if (lane == 0) auxW[w] = s;
        __syncthreads();
        if (bh == 0 && t == 0) {
            float a = 0.f;
            #pragma unroll
            for (int i = 0; i < 8; ++i) a += auxW[i];
            out[(size_t)BB * HH * TT * DD] =
                a * (1.0f / (float)(BB * HH * 2 * TT * DD));
        }

        // exclusive scan over counts[bh] via shfl
        const int* cb = counts + (size_t)bh * TT;
        int* ob = offs + (size_t)bh * TT;
        int loc[8]; int sum = 0;
        #pragma unroll
        for (int i = 0; i < 8; ++i) { loc[i] = sum; sum += cb[t * 8 + i]; }
        int incl = sum;
        #pragma unroll
        for (int off = 1; off < 64; off <<= 1) {
            int o = __shfl_up(incl, off);
            if (lane >= off) incl += o;
        }
        if (lane == 63) wsum[w] = incl;
        __syncthreads();
        if (t < 8) {
            int v2 = wsum[t];
            int inc2 = v2;
            #pragma unroll
            for (int off = 1; off < 8; off <<= 1) {
                int o = __shfl_up(inc2, off);
                if (t >= off) inc2 += o;
            }
            wsum[t] = inc2 - v2;                 // exclusive
        }
        __syncthreads();
        int ex = wsum[w] + incl - sum;
        #pragma unroll
        for (int i = 0; i < 8; ++i) {
            int o = ex + loc[i];
            ob[t * 8 + i] = o;
            offsL[t * 8 + i] = o;
            curL[t * 8 + i] = 0;
        }
        __syncthreads();

        // CSR fill (LDS atomics)
        const int* iq = idxQ + ((size_t)bh << 13);
        int* cs = csr + ((size_t)bh << 13);
        for (int i = t; i < 8192; i += 512) {
            int tok = iq[i];
            int p = offsL[tok] + atomicAdd(&curL[tok], 1);
            cs[p] = i;
        }
        return;
    }

    // ================= attn path ================================================
    unsigned short* KsS = (unsigned short*)smemRaw;            // 130*64 = 16640 B
    unsigned short* VtS = (unsigned short*)(smemRaw + 16640);  // 64*168*2 = 21504 B

    // XCD-bijective swizzle (2048 % 8 == 0): 256 consecutive blks per XCD
    int blk = (bid & 7) * 256 + (bid >> 3);
    int c = blk % NCC;
    int bh = blk / NCC;
    int h = bh % HH;

    int tid = threadIdx.x;
    int w = tid >> 6, l = tid & 63;
    int lr = l & 15, lg = l >> 4;

    const float* memK = mem_key   + ((size_t)h * NCC + c) * (MEMN * DD);
    const float* memV = mem_value + ((size_t)h * NCC + c) * (MEMN * DD);

    // ---- entry: resolve staging rows + issue ALL token-index gathers ----
    int stRow[3], stCh[3];
    const float *vsrcR[3], *ksrcR[3];
    #pragma unroll
    for (int s = 0; s < 3; ++s) {
        int idx = tid + s * 512;
        stRow[s] = idx >> 3; stCh[s] = idx & 7;
        vsrcR[s] = nullptr; ksrcR[s] = nullptr;
        if (idx < 1280 && stRow[s] < KVW) {
            if (stRow[s] == 0) { vsrcR[s] = memV; ksrcR[s] = memK; }
            else {
                int tk = idxK[(size_t)blk * WSZW + stRow[s] - 1];
                vsrcR[s] = v + ((size_t)bh * TT + tk) * DD;
                ksrcR[s] = k + ((size_t)bh * TT + tk) * DD;
            }
        }
    }

    // ---- Q frags (independent chase, overlaps everything) ----
    bf16x8 qf[2];
    {
        int tq = idxQ[(size_t)blk * WSZW + w * 16 + lr];
        const float* qp = q + ((size_t)bh * TT + tq) * DD;
        #pragma unroll
        for (int ks = 0; ks < 2; ++ks) {
            float4 a = *(const float4*)(qp + ks * 32 + lg * 8);
            float4 b = *(const float4*)(qp + ks * 32 + lg * 8 + 4);
            qf[ks] = pack8(a, b);
        }
    }

    // ---- V gather window (batched) ----
    uint4 vw[3];
    #pragma unroll
    for (int s = 0; s < 3; ++s) {
        vw[s] = (uint4){0,0,0,0};
        if (vsrcR[s]) {
            float4 a = *(const float4*)(vsrcR[s] + stCh[s] * 8);
            float4 b = *(const float4*)(vsrcR[s] + stCh[s] * 8 + 4);
            vw[s].x = pk2(a.x, a.y); vw[s].y = pk2(a.z, a.w);
            vw[s].z = pk2(b.x, b.y); vw[s].w = pk2(b.z, b.w);
        }
    }
    // ---- K gather window (batched) ----
    uint4 kw[3];
    #pragma unroll
    for (int s = 0; s < 3; ++s) {
        kw[s] = (uint4){0,0,0,0};
        if (ksrcR[s]) {
            float4 a = *(const float4*)(ksrcR[s] + stCh[s] * 8);
            float4 b = *(const float4*)(ksrcR[s] + stCh[s] * 8 + 4);
            kw[s].x = pk2(a.x, a.y); kw[s].y = pk2(a.z, a.w);
            kw[s].z = pk2(b.x, b.y); kw[s].w = pk2(b.z, b.w);
        }
    }

    // ---- P1: V -> row-major swizzled (valid rows only) ----
    #pragma unroll
    for (int s = 0; s < 3; ++s)
        if (vsrcR[s])
            *reinterpret_cast<uint4*>(
                &KsS[stRow[s] * 64 + ((stCh[s] ^ (stRow[s] & 7)) * 8)]) = vw[s];
    __syncthreads();

    // ---- P2: Vt column segments -> regs (clamped rows; broadcast-class) ----
    unsigned short vreg[3][8];
    #pragma unroll
    for (int s = 0; s < 3; ++s) {
        int idx = tid + s * 512;
        if (idx < 1280) {
            int d = idx & 63, rowblk = idx >> 6;
            #pragma unroll
            for (int i = 0; i < 8; ++i) {
                int row = rowblk * 8 + i;
                int pr = (row < KVW) ? row : 128;
                vreg[s][i] = KsS[pr * 64 + (((d >> 3) ^ (pr & 7)) * 8) + (d & 7)];
            }
        }
    }
    __syncthreads();

    // ---- P3: write Vt (b128 rows) + K (valid rows only) ----
    #pragma unroll
    for (int s = 0; s < 3; ++s) {
        int idx = tid + s * 512;
        if (idx < 1280) {
            int d = idx & 63, rowblk = idx >> 6;
            uint4 ow;
            ow.x = (unsigned)vreg[s][0] | ((unsigned)vreg[s][1] << 16);
            ow.y = (unsigned)vreg[s][2] | ((unsigned)vreg[s][3] << 16);
            ow.z = (unsigned)vreg[s][4] | ((unsigned)vreg[s][5] << 16);
            ow.w = (unsigned)vreg[s][6] | ((unsigned)vreg[s][7] << 16);
            *reinterpret_cast<uint4*>(&VtS[d * 168 + rowblk * 8]) = ow;
        }
    }
    #pragma unroll
    for (int s = 0; s < 3; ++s)
        if (ksrcR[s])
            *reinterpret_cast<uint4*>(
                &KsS[stRow[s] * 64 + ((stCh[s] ^ (stRow[s] & 7)) * 8)]) = kw[s];
    __syncthreads();

    // ---- compute (swapped QK^T, P in regs, Vt b128 B-frags) ----
    f32x4 acc[4];
    #pragma unroll
    for (int dt = 0; dt < 4; ++dt) acc[dt] = (f32x4){0.f, 0.f, 0.f, 0.f};
    float s_sum = 0.f;

    int src0 = lr + ((lg & 1) * 2) * 16;
    int src1 = src0 + 16;
    bool hi = (lg >> 1) != 0;

    for (int kb = 0; kb < 5; ++kb) {
        bf16x8 kf[2][2];
        #pragma unroll
        for (int kvt = 0; kvt < 2; ++kvt)
            #pragma unroll
            for (int ks = 0; ks < 2; ++ks) {
                int row = kb * 32 + kvt * 16 + lr;
                int pr = (row < KVW) ? row : 128;
                int phys = (ks * 4 + lg) ^ (pr & 7);
                kf[kvt][ks] = *reinterpret_cast<const bf16x8*>(&KsS[pr * 64 + phys * 8]);
            }
        __builtin_amdgcn_s_setprio(1);
        unsigned pk[2][2];
        #pragma unroll
        for (int kvt = 0; kvt < 2; ++kvt) {
            f32x4 sf = __builtin_amdgcn_mfma_f32_16x16x32_bf16(
                kf[kvt][0], qf[0], (f32x4){0.f,0.f,0.f,0.f}, 0, 0, 0);
            sf = __builtin_amdgcn_mfma_f32_16x16x32_bf16(kf[kvt][1], qf[1], sf, 0, 0, 0);
            float e[4];
            #pragma unroll
            for (int r = 0; r < 4; ++r) {
                int kv = kb * 32 + kvt * 16 + lg * 4 + r;
                e[r] = (kv < KVW) ? __expf(sf[r] * SCALE) : 0.f;
                s_sum += e[r];
            }
            pk[kvt][0] = pk2(e[0], e[1]);
            pk[kvt][1] = pk2(e[2], e[3]);
        }
        unsigned a00 = __shfl(pk[0][0], src0), a01 = __shfl(pk[0][1], src0);
        unsigned a10 = __shfl(pk[1][0], src0), a11 = __shfl(pk[1][1], src0);
        unsigned b00 = __shfl(pk[0][0], src1), b01 = __shfl(pk[0][1], src1);
        unsigned b10 = __shfl(pk[1][0], src1), b11 = __shfl(pk[1][1], src1);
        union { unsigned u[4]; bf16x8 v; } pu;
        pu.u[0] = hi ? a10 : a00;
        pu.u[1] = hi ? a11 : a01;
        pu.u[2] = hi ? b10 : b00;
        pu.u[3] = hi ? b11 : b01;
        #pragma unroll
        for (int dt = 0; dt < 4; ++dt) {
            bf16x8 vf = *reinterpret_cast<const bf16x8*>(
                &VtS[(dt * 16 + lr) * 168 + kb * 32 + lg * 8]);
            acc[dt] = __builtin_amdgcn_mfma_f32_16x16x32_bf16(pu.v, vf, acc[dt], 0, 0, 0);
        }
        __builtin_amdgcn_s_setprio(0);
    }

    s_sum += __shfl_xor(s_sum, 16);
    s_sum += __shfl_xor(s_sum, 32);
    float sinv[4];
    #pragma unroll
    for (int r = 0; r < 4; ++r)
        sinv[r] = 1.f / __shfl(s_sum, lg * 4 + r);

    // ---- store O as bf16 ----
    #pragma unroll
    for (int r = 0; r < 4; ++r) {
        int row = w * 16 + lg * 4 + r;
        unsigned short* op = so + (((size_t)blk * WSZW + row) * DD);
        #pragma unroll
        for (int dt = 0; dt < 4; ++dt) {
            float ov = acc[dt][r] * sinv[r];
            op[dt * 16 + lr] = (unsigned short)(pk2(ov, ov) & 0xFFFFu);
        }
    }
}

// ---------------- Kernel H: gather-reduce (bf16 so), pair-batched + XCD swz ----
__global__ __launch_bounds__(256) void reduce_kernel(
    const unsigned short* __restrict__ so, const int* __restrict__ counts,
    const int* __restrict__ offs, const int* __restrict__ csr,
    float* __restrict__ out)
{
    int b0 = blockIdx.x;
    int b = (b0 & 7) * 4096 + (b0 >> 3);     // 32768 % 8 == 0 -> bijective
    int gt = b * 4 + (threadIdx.x >> 6);
    int lane = threadIdx.x & 63;
    int bh = gt >> 12;
    int n = counts[gt];
    int st = offs[gt];
    const int* cs = csr + ((size_t)bh << 13);
    const unsigned short* sob = so + (((size_t)bh << 13) * DD);
    float acc = 0.f;
    int j = 0;
    for (; j + 2 <= n; j += 2) {             // pair-batched: 2 idx, then 2 rows
        int s0 = cs[st + j], s1 = cs[st + j + 1];
        float v0 = bf2f(sob[(size_t)s0 * DD + lane]);
        float v1 = bf2f(sob[(size_t)s1 * DD + lane]);
        acc += v0 + v1;
    }
    if (j < n) acc += bf2f(sob[(size_t)cs[st + j] * DD + lane]);
    out[(size_t)gt * DD + lane] = acc / ((float)n + EPSF);
}

extern "C" void kernel_launch(void* const* d_in, const int* in_sizes, int n_in,
                              void* d_out, int out_size, void* d_ws, size_t ws_size,
                              hipStream_t stream) {
    const float* q        = (const float*)d_in[0];
    const float* k        = (const float*)d_in[1];
    const float* v        = (const float*)d_in[2];
    const float* means    = (const float*)d_in[3];
    const float* mem_key  = (const float*)d_in[4];
    const float* mem_val  = (const float*)d_in[5];
    float* out = (float*)d_out;

    const size_t nRows = (size_t)BB * HH * NCC;             // 2048
    const size_t nTok  = (size_t)BB * HH * TT;              // 131072
    const size_t nDist = (size_t)BB * HH * NCC * TT;        // 16777216
    unsigned short* distsQ = (unsigned short*)d_ws;         // bf16, 16.7M (distsK contiguous after)
    unsigned short* distsK = distsQ + nDist;
    unsigned short* so     = distsQ;                        // bf16, aliases dists (written after rescore)
    int*   idxQ   = (int*)(distsK + nDist);                 // 262144 i
    int*   idxK   = idxQ + nRows * WSZW;                    // 262144 i
    int*   counts = idxK + nRows * WSZW;                    // 131072 i (zeroed in dists_kernel)
    float* auxp   = (float*)(counts + nTok);                // 4096 f (per-block partials)
    int*   offs   = (int*)(auxp + 4096);                    // 131072 i
    int*   csr    = offs + nTok;                            // 262144 i
    uintptr_t ip  = (uintptr_t)(csr + nTok * 2);
    ip = (ip + 15) & ~(uintptr_t)15;
    double* invn  = (double*)ip;                            // 2*131072 d (Q then K)

    dists_kernel<<<dim3(BB * HH * (2 * TT / 64)), dim3(256), 0, stream>>>(
        q, k, means, distsQ, distsK, auxp, invn, counts);
    topk_rescore_kernel<<<dim3((unsigned)(2 * nRows)), dim3(512), 0, stream>>>(
        distsQ, q, k, means, invn, idxQ, idxK, counts);
    attn_scanfill_kernel<<<dim3((unsigned)(nRows + BB * HH)), dim3(512), 0, stream>>>(
        q, k, v, mem_key, mem_val, idxQ, idxK, so,
        counts, offs, csr, auxp, out);
    reduce_kernel<<<dim3((unsigned)(nTok / 4)), dim3(256), 0, stream>>>(
        so, counts, offs, csr, out);
}

// Round 31
// 157.096 us; speedup vs baseline: 1.0945x; 1.0118x over previous
//
#include <hip/hip_runtime.h>
#include <math.h>

#define BB 4
#define HH 8
#define TT 4096
#define DD 64
#define NCC 64
#define WSZW 128
#define TPK 160          // widened bf16 top-k; f64 rescore picks exact top-128
#define MEMN 1
#define KVW (MEMN + WSZW)   // 129
constexpr float EPSF = 1e-5f;
constexpr float SCALE = 0.125f;  // 64^-0.5

typedef __attribute__((ext_vector_type(8))) short bf16x8;
typedef __attribute__((ext_vector_type(4))) float f32x4;

// HW packed f32->bf16 (RNE), 1 instruction vs ~7 for the manual bit-twiddle
static __device__ __forceinline__ unsigned int pk2(float a, float b) {
    unsigned int r;
    asm("v_cvt_pk_bf16_f32 %0, %1, %2" : "=v"(r) : "v"(a), "v"(b));
    return r;
}
static __device__ __forceinline__ bf16x8 pack8(float4 a, float4 b) {
    union { unsigned int u[4]; bf16x8 v; } r;
    r.u[0] = pk2(a.x, a.y); r.u[1] = pk2(a.z, a.w);
    r.u[2] = pk2(b.x, b.y); r.u[3] = pk2(b.z, b.w);
    return r.v;
}
static __device__ __forceinline__ unsigned mono16(unsigned u) {
    return (u ^ ((u & 0x8000u) ? 0xFFFFu : 0x8000u)) & 0xFFFFu;
}
static __device__ __forceinline__ unsigned long long mono64(double d) {
    unsigned long long b = (unsigned long long)__double_as_longlong(d);
    return b ^ (((long long)b < 0) ? ~0ULL : 0x8000000000000000ULL);
}
static __device__ __forceinline__ float bf2f(unsigned short u) {
    return __uint_as_float(((unsigned)u) << 16);
}

// ---------------- Kernel A: dists via split-bf16 MFMA -> bf16 dists ------------
__global__ __launch_bounds__(256, 4) void dists_kernel(
    const float* __restrict__ q, const float* __restrict__ k,
    const float* __restrict__ means,
    unsigned short* __restrict__ distsQ, unsigned short* __restrict__ distsK,
    float* __restrict__ aux_part, double* __restrict__ invn,
    int* __restrict__ counts)
{
    __shared__ __align__(16) unsigned short mhS[64 * 64];   // [c][d] swizzled chunks
    __shared__ __align__(16) unsigned short mlS[64 * 64];
    __shared__ __align__(16) unsigned short xhS[64 * 64];   // [tok][d]
    __shared__ __align__(16) unsigned short xlS[64 * 64];
    __shared__ float mqS[64];      // per-cluster ||m||^2
    __shared__ float ssnS[64];     // per-token ||xn||^2
    __shared__ float wMaxS[64 * 5];
    __shared__ int   wIdxS[64 * 5];

    const int chunks = (2 * TT) / 64;          // 128
    int bid0 = blockIdx.x;                     // 4096
    int bid = (bid0 & 7) * 512 + (bid0 >> 3);  // XCD-contiguous (4096 % 8 == 0)
    int bh = bid / chunks;
    int chunk = bid % chunks;
    int h = bh % HH;
    bool isQ = chunk < (TT / 64);
    int tbase = (isQ ? chunk : chunk - 64) * 64;
    const float* src = (isQ ? q : k) + ((size_t)bh * TT + tbase) * DD;
    unsigned short* dst = isQ ? distsQ : distsK;
    double* invdst = invn + (isQ ? 0 : (size_t)BB * HH * TT) + (size_t)bh * TT + tbase;

    int tid = threadIdx.x;

    // zero counts (replaces host memset): 4096 blocks x 32 ints = 131072
    if (tid < 32) counts[(size_t)bid0 * 32 + tid] = 0;

    int row = tid >> 2, part = tid & 3;        // row = cluster idx AND token idx

    // ---- stage means hi/lo (swizzled) + ||m||^2 ----
    {
        const float* mp = means + ((size_t)h * NCC + row) * DD + part * 16;
        float f[16];
        float msq = 0.f;
        #pragma unroll
        for (int i = 0; i < 4; ++i) {
            float4 va = *(const float4*)(mp + i * 4);
            f[i*4] = va.x; f[i*4+1] = va.y; f[i*4+2] = va.z; f[i*4+3] = va.w;
            msq += va.x*va.x + va.y*va.y + va.z*va.z + va.w*va.w;
        }
        msq += __shfl_xor(msq, 1);
        msq += __shfl_xor(msq, 2);
        if (part == 0) mqS[row] = msq;
        #pragma unroll
        for (int cc = 0; cc < 2; ++cc) {
            unsigned hw[4], lw[4];
            #pragma unroll
            for (int j2 = 0; j2 < 4; ++j2) {
                float a = f[cc*8 + j2*2], b = f[cc*8 + j2*2 + 1];
                unsigned p = pk2(a, b);
                float ha = __uint_as_float(p << 16);
                float hb = __uint_as_float(p & 0xFFFF0000u);
                hw[j2] = p; lw[j2] = pk2(a - ha, b - hb);
            }
            int ch = part * 2 + cc;
            int phys = ch ^ (row & 7);
            *reinterpret_cast<uint4*>(&mhS[row * 64 + phys * 8]) = (uint4){hw[0],hw[1],hw[2],hw[3]};
            *reinterpret_cast<uint4*>(&mlS[row * 64 + phys * 8]) = (uint4){lw[0],lw[1],lw[2],lw[3]};
        }
    }
    // ---- stage xn hi/lo (swizzled); f64 norm -> invn + ssn ----
    {
        const float* xp = src + (size_t)row * DD + part * 16;
        float f[16];
        double ssd = 0.0;
        #pragma unroll
        for (int i = 0; i < 4; ++i) {
            float4 va = *(const float4*)(xp + i * 4);
            f[i*4] = va.x; f[i*4+1] = va.y; f[i*4+2] = va.z; f[i*4+3] = va.w;
            ssd += (double)va.x*va.x + (double)va.y*va.y
                 + (double)va.z*va.z + (double)va.w*va.w;
        }
        ssd += __shfl_xor(ssd, 1);
        ssd += __shfl_xor(ssd, 2);
        double invd = 1.0 / fmax(sqrt(ssd), 1e-12);
        if (part == 0) {
            invdst[row] = invd;
            ssnS[row] = (float)(ssd * invd * invd);
        }
        float inv = (float)invd;
        #pragma unroll
        for (int i = 0; i < 16; ++i) f[i] *= inv;
        #pragma unroll
        for (int cc = 0; cc < 2; ++cc) {
            unsigned hw[4], lw[4];
            #pragma unroll
            for (int j2 = 0; j2 < 4; ++j2) {
                float a = f[cc*8 + j2*2], b = f[cc*8 + j2*2 + 1];
                unsigned p = pk2(a, b);
                float ha = __uint_as_float(p << 16);
                float hb = __uint_as_float(p & 0xFFFF0000u);
                hw[j2] = p; lw[j2] = pk2(a - ha, b - hb);
            }
            int ch = part * 2 + cc;
            int phys = ch ^ (row & 7);
            *reinterpret_cast<uint4*>(&xhS[row * 64 + phys * 8]) = (uint4){hw[0],hw[1],hw[2],hw[3]};
            *reinterpret_cast<uint4*>(&xlS[row * 64 + phys * 8]) = (uint4){lw[0],lw[1],lw[2],lw[3]};
        }
    }
    __syncthreads();

    int l = tid & 63, w = tid >> 6;
    int lr = l & 15, lg = l >> 4;

    // ---- A frags: cluster tile w (reused across all 4 token tiles) ----
    bf16x8 mhF[2], mlF[2];
    #pragma unroll
    for (int ks = 0; ks < 2; ++ks) {
        int r2 = w * 16 + lr;
        int phys = (ks * 4 + lg) ^ (r2 & 7);
        mhF[ks] = *reinterpret_cast<const bf16x8*>(&mhS[r2 * 64 + phys * 8]);
        mlF[ks] = *reinterpret_cast<const bf16x8*>(&mlS[r2 * 64 + phys * 8]);
    }

    // ---- GEMM: D[c = w*16+lg*4+r][tok = tt*16+lr], 6 mfma per token tile ----
    f32x4 accT[4];
    size_t rowb = (size_t)(bh * NCC) * TT;
    #pragma unroll
    for (int tt = 0; tt < 4; ++tt) {
        bf16x8 xhF[2], xlF[2];
        #pragma unroll
        for (int ks = 0; ks < 2; ++ks) {
            int r2 = tt * 16 + lr;
            int phys = (ks * 4 + lg) ^ (r2 & 7);
            xhF[ks] = *reinterpret_cast<const bf16x8*>(&xhS[r2 * 64 + phys * 8]);
            xlF[ks] = *reinterpret_cast<const bf16x8*>(&xlS[r2 * 64 + phys * 8]);
        }
        f32x4 a = (f32x4){0.f, 0.f, 0.f, 0.f};
        #pragma unroll
        for (int ks = 0; ks < 2; ++ks)
            a = __builtin_amdgcn_mfma_f32_16x16x32_bf16(mhF[ks], xhF[ks], a, 0, 0, 0);
        #pragma unroll
        for (int ks = 0; ks < 2; ++ks)
            a = __builtin_amdgcn_mfma_f32_16x16x32_bf16(mhF[ks], xlF[ks], a, 0, 0, 0);
        #pragma unroll
        for (int ks = 0; ks < 2; ++ks)
            a = __builtin_amdgcn_mfma_f32_16x16x32_bf16(mlF[ks], xhF[ks], a, 0, 0, 0);
        accT[tt] = a;
        #pragma unroll
        for (int r2 = 0; r2 < 4; ++r2) {
            int c = w * 16 + lg * 4 + r2;
            dst[rowb + (size_t)c * TT + tbase + tt * 16 + lr] =
                (unsigned short)(pk2(a[r2], a[r2]) & 0xFFFFu);
        }
    }

    // ---- argmax via shuffles (lane: token tt*16+lr, clusters w*16+lg*4+r) ----
    #pragma unroll
    for (int tt = 0; tt < 4; ++tt) {
        float bv = accT[tt][0]; int bc = w * 16 + lg * 4;
        #pragma unroll
        for (int r2 = 1; r2 < 4; ++r2)
            if (accT[tt][r2] > bv) { bv = accT[tt][r2]; bc = w * 16 + lg * 4 + r2; }
        #pragma unroll
        for (int off = 16; off <= 32; off <<= 1) {
            float ov = __shfl_xor(bv, off);
            int   oc = __shfl_xor(bc, off);
            if (ov > bv || (ov == bv && oc < bc)) { bv = ov; bc = oc; }
        }
        if (lg == 0) {
            wMaxS[(tt * 16 + lr) * 5 + w] = bv;
            wIdxS[(tt * 16 + lr) * 5 + w] = bc;
        }
    }
    __syncthreads();

    if (tid < 64) {
        float bv = -1e30f; int bc = 0;
        #pragma unroll
        for (int w2 = 0; w2 < 4; ++w2) {   // ascending cluster ranges
            float ov = wMaxS[tid * 5 + w2];
            int   oc = wIdxS[tid * 5 + w2];
            if (ov > bv || (ov == bv && oc < bc)) { bv = ov; bc = oc; }
        }
        float auxv = ssnS[tid] + mqS[bc] - 2.f * bv;
        #pragma unroll
        for (int off = 32; off; off >>= 1) auxv += __shfl_xor(auxv, off);
        if (tid == 0) aux_part[bid] = auxv;
    }
}

// ---------------- Kernel B: fused topk (LDS candidates) + f64 rescore ----------
// Per block = one (side,row): 2-pass 12/4 radix topk writes the 160-candidate
// set to LDS; f64 rescore (4 lanes/candidate, 2 passes -- key order bit-stable
// vs r28/r30); rank re-partitioned to 8 lanes/candidate, 3 passes of 20-iter
// scans (60-iter critical path vs 80) -- pure integer work on unchanged keys.
__global__ __launch_bounds__(512) void topk_rescore_kernel(
    const unsigned short* __restrict__ dists,
    const float* __restrict__ q, const float* __restrict__ k,
    const float* __restrict__ means, const double* __restrict__ invn,
    int* __restrict__ idxQ, int* __restrict__ idxK,
    int* __restrict__ counts)
{
    int bid = blockIdx.x;
    int rid = (bid & 7) * 512 + (bid >> 3);   // 4096 % 8 == 0 -> bijective
    int side = rid >> 11;            // 0=Q, 1=K
    int row = rid & 2047;            // bh*NC + c
    int c = row & (NCC - 1);
    int bh = row >> 6;
    int h = bh % HH;

    const unsigned short* dv = dists + ((size_t)side * 2048 + row) * TT;
    int* outIdx = (side ? idxK : idxQ) + (size_t)row * WSZW;
    const float* xbase = (side ? k : q) + (size_t)bh * TT * DD;
    const double* invp = invn + (side ? (size_t)BB * HH * TT : 0) + (size_t)bh * TT;

    __shared__ int hist[4096];
    __shared__ int wtot[8];
    __shared__ int binSel, tgtS;
    __shared__ int nGtS, posS, eqPos;
    __shared__ int candL[TPK];
    __shared__ double   mD[DD];
    __shared__ unsigned hiS[TPK];
    __shared__ unsigned loS[TPK];
    __shared__ int      kiS[TPK];

    int t = threadIdx.x;
    int lane = t & 63, w = t >> 6;            // 8 waves

    // stage means f64 early (covered by topk barriers before first use)
    if (t < DD) mD[t] = (double)means[((size_t)h * NCC + c) * DD + t];

    // packed mono16: both bf16 halves per dword in one shift/mask/mul/xor
    // r_half = p_half ^ 0x8000 ^ (sign(p_half) * 0x7FFF)  == mono16(p_half)
    unsigned u[8];
    {
        uint4 a = *(const uint4*)(dv + t * 8);
        unsigned ws[4] = {a.x, a.y, a.z, a.w};
        #pragma unroll
        for (int i = 0; i < 4; ++i) {
            unsigned p = ws[i];
            unsigned n = (p >> 15) & 0x00010001u;
            unsigned r = p ^ 0x80008000u ^ (n * 0x7FFFu);
            u[i*2]   = r & 0xFFFFu;
            u[i*2+1] = r >> 16;
        }
    }

    int target = TPK;

    // ---- pass 1: top 12 bits over 4096 bins ----
    {
        int4* hz = (int4*)&hist[t * 8];
        hz[0] = (int4){0,0,0,0}; hz[1] = (int4){0,0,0,0};
        __syncthreads();
        #pragma unroll
        for (int j = 0; j < 8; ++j) atomicAdd(&hist[u[j] >> 4], 1);
        __syncthreads();
        int cnt[8], ls[8];
        {
            const int4* hp = (const int4*)&hist[t * 8];
            int4 c0 = hp[0], c1 = hp[1];
            cnt[0]=c0.x; cnt[1]=c0.y; cnt[2]=c0.z; cnt[3]=c0.w;
            cnt[4]=c1.x; cnt[5]=c1.y; cnt[6]=c1.z; cnt[7]=c1.w;
        }
        int run = 0;
        #pragma unroll
        for (int i = 7; i >= 0; --i) { run += cnt[i]; ls[i] = run; }
        int S = run;
        #pragma unroll
        for (int off = 1; off < 64; off <<= 1) {
            int o = __shfl_down(S, off);
            if (lane + off < 64) S += o;
        }
        if (lane == 0) wtot[w] = S;
        __syncthreads();
        int after = 0;
        for (int ww = w + 1; ww < 8; ++ww) after += wtot[ww];
        int St1 = S - run + after;
        #pragma unroll
        for (int i = 0; i < 8; ++i) {
            int sfxb = ls[i] + St1;
            if (sfxb >= target && sfxb - cnt[i] < target) {
                binSel = t * 8 + i; tgtS = target - (sfxb - cnt[i]);
            }
        }
        __syncthreads();
    }
    unsigned prefix12 = (unsigned)binSel;
    target = tgtS;
    __syncthreads();

    // ---- pass 2: low 4 bits (16 bins, lanes 0-15 of wave 0) ----
    if (t < 16) hist[t] = 0;
    __syncthreads();
    #pragma unroll
    for (int j = 0; j < 8; ++j)
        if ((u[j] >> 4) == prefix12) atomicAdd(&hist[u[j] & 0xF], 1);
    __syncthreads();
    if (t < 16) {
        int cnt = hist[t];
        int S = cnt;
        #pragma unroll
        for (int off = 1; off < 16; off <<= 1) {
            int o = __shfl_down(S, off);
            if (t + off < 16) S += o;
        }
        if (S >= target && S - cnt < target) binSel = t;
    }
    __syncthreads();
    unsigned pivot = (prefix12 << 4) | (unsigned)binSel;

    // ---- epilogue: compact candidates into LDS ----
    if (t == 0) { nGtS = 0; posS = 0; eqPos = 0; }
    __syncthreads();
    int myg = 0;
    #pragma unroll
    for (int j = 0; j < 8; ++j) myg += (u[j] > pivot) ? 1 : 0;
    if (myg) atomicAdd(&nGtS, myg);
    __syncthreads();
    int n_gt = nGtS;
    int n_need = TPK - n_gt;
    #pragma unroll
    for (int j = 0; j < 8; ++j) {
        if (u[j] > pivot) {
            int p = atomicAdd(&posS, 1);
            candL[p] = t * 8 + j;
        } else if (u[j] == pivot) {
            int p = atomicAdd(&eqPos, 1);
            if (p < n_need) candL[n_gt + p] = t * 8 + j;
        }
    }
    __syncthreads();

    // ---- rescore: f64 dot, 4 lanes/candidate, 2 passes (128 + 32 groups) ----
    // (kept bit-identical to the passing r28/r30 summation order)
    int qt = t & 3;
    #pragma unroll
    for (int base = 0; base < TPK; base += 128) {
        int g = base + (t >> 2);
        if (g < TPK) {
            int tok = candL[g];
            const float* xp = xbase + (size_t)tok * DD + qt * 16;
            double inv = invp[tok];
            double d0 = 0.0, d1 = 0.0;
            #pragma unroll
            for (int i = 0; i < 2; ++i) {
                float4 va = *(const float4*)(xp + i * 4);
                int d = qt * 16 + i * 4;
                d0 += (double)va.x * mD[d]   + (double)va.y * mD[d+1]
                    + (double)va.z * mD[d+2] + (double)va.w * mD[d+3];
            }
            #pragma unroll
            for (int i = 2; i < 4; ++i) {
                float4 va = *(const float4*)(xp + i * 4);
                int d = qt * 16 + i * 4;
                d1 += (double)va.x * mD[d]   + (double)va.y * mD[d+1]
                    + (double)va.z * mD[d+2] + (double)va.w * mD[d+3];
            }
            double dot = d0 + d1;
            dot += __shfl_xor(dot, 1); dot += __shfl_xor(dot, 2);
            double vv = dot * inv;
            unsigned long long key = mono64(vv);
            if (qt == 0) {
                hiS[g] = (unsigned)(key >> 32);
                loS[g] = (unsigned)key;
                kiS[g] = tok;
            }
        }
    }
    __syncthreads();

    // ---- rank: 8 lanes/candidate, 3 passes of 20-iter scans ----
    // lanes (t&7) scan disjoint 20-entry blocks (stride-20 addrs -> 8 distinct
    // banks, conflict-free); shfl_xor 1/2/4 folds the 8 partial counts.
    int oct = t & 7;
    #pragma unroll
    for (int base = 0; base < TPK; base += 64) {
        int g = base + (t >> 3);
        if (g < TPK) {
            unsigned myhi = hiS[g], mylo = loS[g];
            int tok = kiS[g];
            int rk = 0, eq = 0;
            #pragma unroll 5
            for (int i = 0; i < TPK / 8; ++i) {
                unsigned hj = hiS[oct * (TPK / 8) + i];
                rk += (hj > myhi) ? 1 : 0;
                eq += (hj == myhi) ? 1 : 0;
            }
            rk += __shfl_xor(rk, 1); rk += __shfl_xor(rk, 2); rk += __shfl_xor(rk, 4);
            eq += __shfl_xor(eq, 1); eq += __shfl_xor(eq, 2); eq += __shfl_xor(eq, 4);
            if (eq > 1) {
                int rk2 = 0;
                for (int i = 0; i < TPK / 8; ++i) {
                    int j = oct * (TPK / 8) + i;
                    unsigned hj = hiS[j];
                    if (hj > myhi) rk2++;
                    else if (hj == myhi) {
                        unsigned lj = loS[j];
                        if (lj > mylo || (lj == mylo && kiS[j] < tok)) rk2++;
                    }
                }
                rk2 += __shfl_xor(rk2, 1); rk2 += __shfl_xor(rk2, 2); rk2 += __shfl_xor(rk2, 4);
                rk = rk2;
            }
            if (oct == 0 && rk < WSZW) {
                outIdx[rk] = tok;
                if (side == 0) atomicAdd(&counts[bh * TT + tok], 1);
            }
        }
    }
}

// ---------------- Kernel C: fused attn (blocks 0..2047) + scanfill (2048..2079) -
__global__ __launch_bounds__(512, 8) void attn_scanfill_kernel(
    const float* __restrict__ q, const float* __restrict__ k, const float* __restrict__ v,
    const float* __restrict__ mem_key, const float* __restrict__ mem_value,
    const int* __restrict__ idxQ, const int* __restrict__ idxK,
    unsigned short* __restrict__ so,
    const int* __restrict__ counts, int* __restrict__ offs, int* __restrict__ csr,
    const float* __restrict__ auxp, float* __restrict__ out)
{
    __shared__ __align__(16) unsigned char smemRaw[38144];
    int bid = blockIdx.x;

    if (bid >= 2048) {
        // ================= scanfill path (512 threads, 8 waves) =================
        int bh = bid - 2048;
        int t = threadIdx.x;
        int lane = t & 63, w = t >> 6;
        int* offsL = (int*)smemRaw;                   // 16384 B
        int* curL  = (int*)(smemRaw + 16384);         // 16384 B
        int* wsum  = (int*)(smemRaw + 32768);         // 32 B
        float* auxW = (float*)(smemRaw + 32800);      // 32 B

        // aux fold (loads only on bh==0; uniform barriers)
        float s = 0.f;
        if (bh == 0)
            for (int i = t; i < 4096; i += 512) s += auxp[i];
        #pragma unroll
        for (int off = 32; off; off >>= 1) s += __shfl_xor(s, off);
        if (lane == 0) auxW[w] = s;
        __syncthreads();
        if (bh == 0 && t == 0) {
            float a = 0.f;
            #pragma unroll
            for (int i = 0; i < 8; ++i) a += auxW[i];
            out[(size_t)BB * HH * TT * DD] =
                a * (1.0f / (float)(BB * HH * 2 * TT * DD));
        }

        // exclusive scan over counts[bh] via shfl
        const int* cb = counts + (size_t)bh * TT;
        int* ob = offs + (size_t)bh * TT;
        int loc[8]; int sum = 0;
        #pragma unroll
        for (int i = 0; i < 8; ++i) { loc[i] = sum; sum += cb[t * 8 + i]; }
        int incl = sum;
        #pragma unroll
        for (int off = 1; off < 64; off <<= 1) {
            int o = __shfl_up(incl, off);
            if (lane >= off) incl += o;
        }
        if (lane == 63) wsum[w] = incl;
        __syncthreads();
        if (t < 8) {
            int v2 = wsum[t];
            int inc2 = v2;
            #pragma unroll
            for (int off = 1; off < 8; off <<= 1) {
                int o = __shfl_up(inc2, off);
                if (t >= off) inc2 += o;
            }
            wsum[t] = inc2 - v2;                 // exclusive
        }
        __syncthreads();
        int ex = wsum[w] + incl - sum;
        #pragma unroll
        for (int i = 0; i < 8; ++i) {
            int o = ex + loc[i];
            ob[t * 8 + i] = o;
            offsL[t * 8 + i] = o;
            curL[t * 8 + i] = 0;
        }
        __syncthreads();

        // CSR fill (LDS atomics)
        const int* iq = idxQ + ((size_t)bh << 13);
        int* cs = csr + ((size_t)bh << 13);
        for (int i = t; i < 8192; i += 512) {
            int tok = iq[i];
            int p = offsL[tok] + atomicAdd(&curL[tok], 1);
            cs[p] = i;
        }
        return;
    }

    // ================= attn path ================================================
    unsigned short* KsS = (unsigned short*)smemRaw;            // 130*64 = 16640 B
    unsigned short* VtS = (unsigned short*)(smemRaw + 16640);  // 64*168*2 = 21504 B

    // XCD-bijective swizzle (2048 % 8 == 0): 256 consecutive blks per XCD
    int blk = (bid & 7) * 256 + (bid >> 3);
    int c = blk % NCC;
    int bh = blk / NCC;
    int h = bh % HH;

    int tid = threadIdx.x;
    int w = tid >> 6, l = tid & 63;
    int lr = l & 15, lg = l >> 4;

    const float* memK = mem_key   + ((size_t)h * NCC + c) * (MEMN * DD);
    const float* memV = mem_value + ((size_t)h * NCC + c) * (MEMN * DD);

    // ---- entry: resolve staging rows + issue ALL token-index gathers ----
    int stRow[3], stCh[3];
    const float *vsrcR[3], *ksrcR[3];
    #pragma unroll
    for (int s = 0; s < 3; ++s) {
        int idx = tid + s * 512;
        stRow[s] = idx >> 3; stCh[s] = idx & 7;
        vsrcR[s] = nullptr; ksrcR[s] = nullptr;
        if (idx < 1280 && stRow[s] < KVW) {
            if (stRow[s] == 0) { vsrcR[s] = memV; ksrcR[s] = memK; }
            else {
                int tk = idxK[(size_t)blk * WSZW + stRow[s] - 1];
                vsrcR[s] = v + ((size_t)bh * TT + tk) * DD;
                ksrcR[s] = k + ((size_t)bh * TT + tk) * DD;
            }
        }
    }

    // ---- Q frags (independent chase, overlaps everything) ----
    bf16x8 qf[2];
    {
        int tq = idxQ[(size_t)blk * WSZW + w * 16 + lr];
        const float* qp = q + ((size_t)bh * TT + tq) * DD;
        #pragma unroll
        for (int ks = 0; ks < 2; ++ks) {
            float4 a = *(const float4*)(qp + ks * 32 + lg * 8);
            float4 b = *(const float4*)(qp + ks * 32 + lg * 8 + 4);
            qf[ks] = pack8(a, b);
        }
    }

    // ---- V gather window (batched) ----
    uint4 vw[3];
    #pragma unroll
    for (int s = 0; s < 3; ++s) {
        vw[s] = (uint4){0,0,0,0};
        if (vsrcR[s]) {
            float4 a = *(const float4*)(vsrcR[s] + stCh[s] * 8);
            float4 b = *(const float4*)(vsrcR[s] + stCh[s] * 8 + 4);
            vw[s].x = pk2(a.x, a.y); vw[s].y = pk2(a.z, a.w);
            vw[s].z = pk2(b.x, b.y); vw[s].w = pk2(b.z, b.w);
        }
    }
    // ---- K gather window (batched) ----
    uint4 kw[3];
    #pragma unroll
    for (int s = 0; s < 3; ++s) {
        kw[s] = (uint4){0,0,0,0};
        if (ksrcR[s]) {
            float4 a = *(const float4*)(ksrcR[s] + stCh[s] * 8);
            float4 b = *(const float4*)(ksrcR[s] + stCh[s] * 8 + 4);
            kw[s].x = pk2(a.x, a.y); kw[s].y = pk2(a.z, a.w);
            kw[s].z = pk2(b.x, b.y); kw[s].w = pk2(b.z, b.w);
        }
    }

    // ---- P1: V -> row-major swizzled (valid rows only) ----
    #pragma unroll
    for (int s = 0; s < 3; ++s)
        if (vsrcR[s])
            *reinterpret_cast<uint4*>(
                &KsS[stRow[s] * 64 + ((stCh[s] ^ (stRow[s] & 7)) * 8)]) = vw[s];
    __syncthreads();

    // ---- P2: Vt column segments -> regs (clamped rows; broadcast-class) ----
    unsigned short vreg[3][8];
    #pragma unroll
    for (int s = 0; s < 3; ++s) {
        int idx = tid + s * 512;
        if (idx < 1280) {
            int d = idx & 63, rowblk = idx >> 6;
            #pragma unroll
            for (int i = 0; i < 8; ++i) {
                int row = rowblk * 8 + i;
                int pr = (row < KVW) ? row : 128;
                vreg[s][i] = KsS[pr * 64 + (((d >> 3) ^ (pr & 7)) * 8) + (d & 7)];
            }
        }
    }
    __syncthreads();

    // ---- P3: write Vt (b128 rows) + K (valid rows only) ----
    #pragma unroll
    for (int s = 0; s < 3; ++s) {
        int idx = tid + s * 512;
        if (idx < 1280) {
            int d = idx & 63, rowblk = idx >> 6;
            uint4 ow;
            ow.x = (unsigned)vreg[s][0] | ((unsigned)vreg[s][1] << 16);
            ow.y = (unsigned)vreg[s][2] | ((unsigned)vreg[s][3] << 16);
            ow.z = (unsigned)vreg[s][4] | ((unsigned)vreg[s][5] << 16);
            ow.w = (unsigned)vreg[s][6] | ((unsigned)vreg[s][7] << 16);
            *reinterpret_cast<uint4*>(&VtS[d * 168 + rowblk * 8]) = ow;
        }
    }
    #pragma unroll
    for (int s = 0; s < 3; ++s)
        if (ksrcR[s])
            *reinterpret_cast<uint4*>(
                &KsS[stRow[s] * 64 + ((stCh[s] ^ (stRow[s] & 7)) * 8)]) = kw[s];
    __syncthreads();

    // ---- compute (swapped QK^T, P in regs, Vt b128 B-frags) ----
    f32x4 acc[4];
    #pragma unroll
    for (int dt = 0; dt < 4; ++dt) acc[dt] = (f32x4){0.f, 0.f, 0.f, 0.f};
    float s_sum = 0.f;

    int src0 = lr + ((lg & 1) * 2) * 16;
    int src1 = src0 + 16;
    bool hi = (lg >> 1) != 0;

    for (int kb = 0; kb < 5; ++kb) {
        bf16x8 kf[2][2];
        #pragma unroll
        for (int kvt = 0; kvt < 2; ++kvt)
            #pragma unroll
            for (int ks = 0; ks < 2; ++ks) {
                int row = kb * 32 + kvt * 16 + lr;
                int pr = (row < KVW) ? row : 128;
                int phys = (ks * 4 + lg) ^ (pr & 7);
                kf[kvt][ks] = *reinterpret_cast<const bf16x8*>(&KsS[pr * 64 + phys * 8]);
            }
        __builtin_amdgcn_s_setprio(1);
        unsigned pk[2][2];
        #pragma unroll
        for (int kvt = 0; kvt < 2; ++kvt) {
            f32x4 sf = __builtin_amdgcn_mfma_f32_16x16x32_bf16(
                kf[kvt][0], qf[0], (f32x4){0.f,0.f,0.f,0.f}, 0, 0, 0);
            sf = __builtin_amdgcn_mfma_f32_16x16x32_bf16(kf[kvt][1], qf[1], sf, 0, 0, 0);
            float e[4];
            #pragma unroll
            for (int r = 0; r < 4; ++r) {
                int kv = kb * 32 + kvt * 16 + lg * 4 + r;
                e[r] = (kv < KVW) ? __expf(sf[r] * SCALE) : 0.f;
                s_sum += e[r];
            }
            pk[kvt][0] = pk2(e[0], e[1]);
            pk[kvt][1] = pk2(e[2], e[3]);
        }
        unsigned a00 = __shfl(pk[0][0], src0), a01 = __shfl(pk[0][1], src0);
        unsigned a10 = __shfl(pk[1][0], src0), a11 = __shfl(pk[1][1], src0);
        unsigned b00 = __shfl(pk[0][0], src1), b01 = __shfl(pk[0][1], src1);
        unsigned b10 = __shfl(pk[1][0], src1), b11 = __shfl(pk[1][1], src1);
        union { unsigned u[4]; bf16x8 v; } pu;
        pu.u[0] = hi ? a10 : a00;
        pu.u[1] = hi ? a11 : a01;
        pu.u[2] = hi ? b10 : b00;
        pu.u[3] = hi ? b11 : b01;
        #pragma unroll
        for (int dt = 0; dt < 4; ++dt) {
            bf16x8 vf = *reinterpret_cast<const bf16x8*>(
                &VtS[(dt * 16 + lr) * 168 + kb * 32 + lg * 8]);
            acc[dt] = __builtin_amdgcn_mfma_f32_16x16x32_bf16(pu.v, vf, acc[dt], 0, 0, 0);
        }
        __builtin_amdgcn_s_setprio(0);
    }

    s_sum += __shfl_xor(s_sum, 16);
    s_sum += __shfl_xor(s_sum, 32);
    float sinv[4];
    #pragma unroll
    for (int r = 0; r < 4; ++r)
        sinv[r] = 1.f / __shfl(s_sum, lg * 4 + r);

    // ---- store O as bf16 ----
    #pragma unroll
    for (int r = 0; r < 4; ++r) {
        int row = w * 16 + lg * 4 + r;
        unsigned short* op = so + (((size_t)blk * WSZW + row) * DD);
        #pragma unroll
        for (int dt = 0; dt < 4; ++dt) {
            float ov = acc[dt][r] * sinv[r];
            op[dt * 16 + lr] = (unsigned short)(pk2(ov, ov) & 0xFFFFu);
        }
    }
}

// ---------------- Kernel H: gather-reduce (bf16 so), pair-batched + XCD swz ----
__global__ __launch_bounds__(256) void reduce_kernel(
    const unsigned short* __restrict__ so, const int* __restrict__ counts,
    const int* __restrict__ offs, const int* __restrict__ csr,
    float* __restrict__ out)
{
    int b0 = blockIdx.x;
    int b = (b0 & 7) * 4096 + (b0 >> 3);     // 32768 % 8 == 0 -> bijective
    int gt = b * 4 + (threadIdx.x >> 6);
    int lane = threadIdx.x & 63;
    int bh = gt >> 12;
    int n = counts[gt];
    int st = offs[gt];
    const int* cs = csr + ((size_t)bh << 13);
    const unsigned short* sob = so + (((size_t)bh << 13) * DD);
    float acc = 0.f;
    int j = 0;
    for (; j + 2 <= n; j += 2) {             // pair-batched: 2 idx, then 2 rows
        int s0 = cs[st + j], s1 = cs[st + j + 1];
        float v0 = bf2f(sob[(size_t)s0 * DD + lane]);
        float v1 = bf2f(sob[(size_t)s1 * DD + lane]);
        acc += v0 + v1;
    }
    if (j < n) acc += bf2f(sob[(size_t)cs[st + j] * DD + lane]);
    out[(size_t)gt * DD + lane] = acc / ((float)n + EPSF);
}

extern "C" void kernel_launch(void* const* d_in, const int* in_sizes, int n_in,
                              void* d_out, int out_size, void* d_ws, size_t ws_size,
                              hipStream_t stream) {
    const float* q        = (const float*)d_in[0];
    const float* k        = (const float*)d_in[1];
    const float* v        = (const float*)d_in[2];
    const float* means    = (const float*)d_in[3];
    const float* mem_key  = (const float*)d_in[4];
    const float* mem_val  = (const float*)d_in[5];
    float* out = (float*)d_out;

    const size_t nRows = (size_t)BB * HH * NCC;             // 2048
    const size_t nTok  = (size_t)BB * HH * TT;              // 131072
    const size_t nDist = (size_t)BB * HH * NCC * TT;        // 16777216
    unsigned short* distsQ = (unsigned short*)d_ws;         // bf16, 16.7M (distsK contiguous after)
    unsigned short* distsK = distsQ + nDist;
    unsigned short* so     = distsQ;                        // bf16, aliases dists (written after rescore)
    int*   idxQ   = (int*)(distsK + nDist);                 // 262144 i
    int*   idxK   = idxQ + nRows * WSZW;                    // 262144 i
    int*   counts = idxK + nRows * WSZW;                    // 131072 i (zeroed in dists_kernel)
    float* auxp   = (float*)(counts + nTok);                // 4096 f (per-block partials)
    int*   offs   = (int*)(auxp + 4096);                    // 131072 i
    int*   csr    = offs + nTok;                            // 262144 i
    uintptr_t ip  = (uintptr_t)(csr + nTok * 2);
    ip = (ip + 15) & ~(uintptr_t)15;
    double* invn  = (double*)ip;                            // 2*131072 d (Q then K)

    dists_kernel<<<dim3(BB * HH * (2 * TT / 64)), dim3(256), 0, stream>>>(
        q, k, means, distsQ, distsK, auxp, invn, counts);
    topk_rescore_kernel<<<dim3((unsigned)(2 * nRows)), dim3(512), 0, stream>>>(
        distsQ, q, k, means, invn, idxQ, idxK, counts);
    attn_scanfill_kernel<<<dim3((unsigned)(nRows + BB * HH)), dim3(512), 0, stream>>>(
        q, k, v, mem_key, mem_val, idxQ, idxK, so,
        counts, offs, csr, auxp, out);
    reduce_kernel<<<dim3((unsigned)(nTok / 4)), dim3(256), 0, stream>>>(
        so, counts, offs, csr, out);
}